// Round 4
// baseline (520.176 us; speedup 1.0000x reference)
//
#include <hip/hip_runtime.h>

typedef unsigned short u16;
typedef short short8 __attribute__((ext_vector_type(8)));
typedef float f32x4 __attribute__((ext_vector_type(4)));

// ---------- helpers ----------
__device__ __forceinline__ u16 f2b(float x){
  union{float f; unsigned u;} v; v.f = x;
  unsigned r = (v.u + 0x7FFFu + ((v.u >> 16) & 1u)) >> 16;
  return (u16)r;
}
__device__ __forceinline__ float b2f(u16 h){
  union{unsigned u; float f;} v; v.u = ((unsigned)h) << 16; return v.f;
}
__device__ __forceinline__ float sigm(float x){ return 1.0f/(1.0f + __expf(-x)); }
__device__ __forceinline__ float tanh_f(float x){ return 1.0f - 2.0f/(1.0f + __expf(2.0f*x)); }

// ---------- prep: xe gather->bf16, Wcomb, bias, Whh pair-split repack, W1 repack, hbt pad zero ----------
__global__ void prep_kernel(const int* __restrict__ x, const float* __restrict__ emb,
   const float* __restrict__ Wih_f, const float* __restrict__ Whh_f,
   const float* __restrict__ bih_f, const float* __restrict__ bhh_f,
   const float* __restrict__ Wih_b, const float* __restrict__ Whh_b,
   const float* __restrict__ bih_b, const float* __restrict__ bhh_b,
   const float* __restrict__ W1,
   u16* __restrict__ xe, u16* __restrict__ wc, float* __restrict__ biasC,
   float* __restrict__ whhP, u16* __restrict__ w1b, u16* __restrict__ hbt)
{
  int id = blockIdx.x*256 + threadIdx.x;
  const int N0 = 32768*128;   // xe  [p][k]
  const int N1 = 832*128;     // wc  [n][k]
  const int N2 = 800;         // biasC
  const int N3 = 83200;       // whhP [d][kk(52)][p(800)]  p=u*8+g*2+half, k=half*50+kk
  const int N4 = 672*320;     // w1b  (id = k*320+n)
  const int N5 = 32768*24;    // hbt pad cols 200..223
  if (id < N0){
    int p = id >> 7, k = id & 127;
    float v = 0.f;
    if (k < 100) v = emb[x[p]*100 + k];
    xe[id] = f2b(v);
    return;
  }
  id -= N0;
  if (id < N1){
    int n = id >> 7, k = id & 127;
    float v = 0.f;
    if (k < 100){
      if (n < 400) v = Wih_f[n*100+k];
      else if (n < 800) v = Wih_b[(n-400)*100+k];
    }
    wc[id] = f2b(v);
    return;
  }
  id -= N1;
  if (id < N2){
    biasC[id] = (id < 400) ? (bih_f[id]+bhh_f[id]) : (bih_b[id-400]+bhh_b[id-400]);
    return;
  }
  id -= N2;
  if (id < N3){
    int d = id / 41600; int rem = id - d*41600; int kk = rem / 800; int p = rem - kk*800;
    int u = p >> 3, g = (p >> 1) & 3, half = p & 1;
    const float* W = d ? Whh_b : Whh_f;
    float v = 0.f;
    if (kk < 50) v = W[(g*100 + u)*100 + half*50 + kk];
    whhP[id] = v;
    return;
  }
  id -= N3;
  if (id < N4){
    int k = id / 320; int n = id - k*320;
    int seg = k / 224; int wwk = k - seg*224;
    float v = 0.f;
    if (n < 300 && wwk < 200) v = W1[(seg*200 + wwk)*300 + n];
    w1b[n*672 + k] = f2b(v);
    return;
  }
  id -= N4;
  if (id < N5){
    int p = id / 24; int k = id - p*24;
    hbt[p*224 + 200 + k] = 0;
  }
}

// ---------- GEMM1: inp[d][b][t][j] = xe @ Wcomb^T + bias, bf16 MFMA ----------
// M=32768 (p=b*128+t), N=832 (pad of 800), K=128 (pad of 100)
__global__ __launch_bounds__(256) void gemm1_kernel(const u16* __restrict__ xe,
    const u16* __restrict__ wc, const float* __restrict__ biasC, u16* __restrict__ inp)
{
  __shared__ __align__(16) u16 As[64*136];   // stride 136: 2-way bank alias only
  __shared__ __align__(16) u16 Bs[64*136];
  const int m0 = blockIdx.x*64, n0 = blockIdx.y*64;
  const int tid = threadIdx.x;
  #pragma unroll
  for (int i=0;i<4;i++){
    int f = i*256 + tid;
    int row = f >> 4, c8 = f & 15;
    *(uint4*)&As[row*136 + c8*8] = *(const uint4*)&xe[(m0+row)*128 + c8*8];
    *(uint4*)&Bs[row*136 + c8*8] = *(const uint4*)&wc[(n0+row)*128 + c8*8];
  }
  __syncthreads();
  const int w = tid >> 6, lane = tid & 63, col = lane & 15, quad = lane >> 4;
  f32x4 acc[4];
  #pragma unroll
  for (int nt=0;nt<4;nt++) acc[nt] = (f32x4){0.f,0.f,0.f,0.f};
  #pragma unroll
  for (int kc=0;kc<4;kc++){
    short8 af = *(const short8*)&As[(w*16+col)*136 + kc*32 + quad*8];
    #pragma unroll
    for (int nt=0;nt<4;nt++){
      short8 bfrag = *(const short8*)&Bs[(nt*16+col)*136 + kc*32 + quad*8];
      acc[nt] = __builtin_amdgcn_mfma_f32_16x16x32_bf16(af, bfrag, acc[nt], 0, 0, 0);
    }
  }
  #pragma unroll
  for (int nt=0;nt<4;nt++){
    int n = n0 + nt*16 + col;
    if (n < 800){
      float bs = biasC[n];
      int dir = (n >= 400) ? 1 : 0;
      int j = n - dir*400;
      #pragma unroll
      for (int r=0;r<4;r++){
        int m = m0 + w*16 + quad*4 + r;
        inp[(dir*32768 + m)*400 + j] = f2b(acc[nt][r] + bs);
      }
    }
  }
}

// ---------- LSTM recurrence: 512 chains (dir,b), one block each ----------
// 800 compute threads: tid -> (u = tid>>3, g = (tid>>1)&3, half = tid&1).
// Each thread holds whh[52] in VGPRs (~85 regs, cap 128 via (832,4) -- fits:
// no AGPR parking, no spill). Per step: 13 broadcast ds_read_b128 of h,
// 52 FMA, pair-sum shfl, then 3 shfl_xor gather i/f/g/o into all 8 lanes of
// the unit-group; cell update computed redundantly in-register.
// ONE barrier per step; h double-buffered by parity in LDS (dual aligned
// copies: region A = h[0..51], region B at +52 = h[50..99]+pad).
__global__ __launch_bounds__(832, 4) void lstm_kernel(const u16* __restrict__ inp,
    const float* __restrict__ whhP, u16* __restrict__ hbt)
{
  __shared__ __align__(16) float hs2[2][104];
  const int cid = blockIdx.x;
  const int b = cid & 255, dir = cid >> 8;
  const int tid = threadIdx.x;
  const int u = tid >> 3, g = (tid >> 1) & 3, half = tid & 1;

  if (tid < 208) ((float*)hs2)[tid] = 0.f;

  float whh[52];
  const u16* ipt = inp;
  u16* hpt = hbt;
  u16 cur = 0;
  float c = 0.f;
  const int t0 = dir ? 127 : 0;
  const int dIp = dir ? -400 : 400;
  const int dHp = dir ? -224 : 224;
  if (tid < 800){
    const float* wp = whhP + dir*41600 + tid;   // [d][kk][p], coalesced over p
    #pragma unroll
    for (int k=0;k<52;k++) whh[k] = wp[k*800];
    ipt = inp + ((size_t)(dir*32768 + b*128 + t0))*400 + g*100 + u;
    hpt = hbt + ((size_t)(b*128 + t0))*224 + dir*100 + u;
    cur = *ipt;           // 1-deep pipeline on the preactivation load
  }
  __syncthreads();

  for (int step=0; step<128; step++){
    const int par = step & 1;
    if (tid < 800){
      float prev = b2f(cur);
      if (step < 127) cur = ipt[dIp];
      ipt += dIp;
      const float4* h4 = (const float4*)&hs2[par][half*52];   // 16B aligned
      float a0=0.f,a1=0.f,a2=0.f,a3=0.f;
      #pragma unroll
      for (int kk=0;kk<13;kk++){
        float4 hv = h4[kk];
        a0 = fmaf(whh[4*kk+0], hv.x, a0);
        a1 = fmaf(whh[4*kk+1], hv.y, a1);
        a2 = fmaf(whh[4*kk+2], hv.z, a2);
        a3 = fmaf(whh[4*kk+3], hv.w, a3);
      }
      float part = (a0+a1)+(a2+a3);
      part += __shfl_xor(part, 1, 64);        // pair-sum over the two k-halves
      float pre = part + prev;
      // gather the 4 gate values of unit u into every lane of the 8-group
      float s2 = __shfl_xor(pre, 2, 64);
      float lo = (g & 1) ? s2 : pre;          // i (g<2) or g-gate (g>=2)
      float hi = (g & 1) ? pre : s2;          // f (g<2) or o       (g>=2)
      float s4l = __shfl_xor(lo, 4, 64);
      float s4h = __shfl_xor(hi, 4, 64);
      float iv = (g & 2) ? s4l : lo;
      float fv = (g & 2) ? s4h : hi;
      float gv = (g & 2) ? lo  : s4l;
      float ov = (g & 2) ? hi  : s4h;
      c = sigm(fv)*c + sigm(iv)*tanh_f(gv);
      float h = sigm(ov)*tanh_f(c);
      float* hw = hs2[par^1];
      if (g == 0){
        if (half == 0){ if (u < 52)  hw[u]   = h; }   // region A: h[0..51]
        else          { if (u >= 50) hw[u+2] = h; }   // region B: h[50..99]
      }
      if (g == 1 && half == 0) *hpt = f2b(h);
      hpt += dHp;
    }
    __syncthreads();
  }
}

// ---------- MLP: gathered bf16 MFMA GEMM + tanh + W2 + softmax fused ----------
// M=65280 (m=b*255+c), N=320 (pad of 300), K=672 (3 segments of 224, valid 200)
__global__ __launch_bounds__(512) void mlp_kernel(const u16* __restrict__ hbt,
    const u16* __restrict__ w1b, const int* __restrict__ paths,
    const float* __restrict__ b1, const float* __restrict__ W2,
    const float* __restrict__ b2, float* __restrict__ out)
{
  __shared__ __align__(16) u16 As[128*40];   // stride 40: 2-way alias only
  __shared__ __align__(16) u16 Bs[320*40];
  const int m0 = blockIdx.x*128;
  const int tid = threadIdx.x;
  const int arow = tid >> 2, ac8 = tid & 3;
  const int am = m0 + arow;
  const int ab = am / 255;   // batch index of this A row
  const int w = tid >> 6, lane = tid & 63, col = lane & 15, quad = lane >> 4;
  f32x4 acc[20];
  #pragma unroll
  for (int nt=0;nt<20;nt++) acc[nt] = (f32x4){0.f,0.f,0.f,0.f};
  for (int kc=0;kc<21;kc++){
    __syncthreads();
    // stage W1 chunk: 320 rows x 32 k
    for (int f = tid; f < 1280; f += 512){
      int br = f >> 2, bc = f & 3;
      *(uint4*)&Bs[br*40 + bc*8] = *(const uint4*)&w1b[br*672 + kc*32 + bc*8];
    }
    // stage gathered A chunk: 128 rows x 32 k (one 16B piece per thread)
    int seg = (kc >= 14) ? 2 : (kc >= 7 ? 1 : 0);
    int ko = kc - seg*7;
    int it = paths[am*3 + seg];
    uint4 v = make_uint4(0u,0u,0u,0u);
    if (it >= 0){
      int t = it > 127 ? 127 : it;
      v = *(const uint4*)&hbt[(ab*128 + t)*224 + ko*32 + ac8*8];
    }
    *(uint4*)&As[arow*40 + ac8*8] = v;
    __syncthreads();
    short8 af = *(const short8*)&As[(w*16+col)*40 + quad*8];
    #pragma unroll
    for (int nt=0;nt<20;nt++){
      short8 bfrag = *(const short8*)&Bs[(nt*16+col)*40 + quad*8];
      acc[nt] = __builtin_amdgcn_mfma_f32_16x16x32_bf16(af, bfrag, acc[nt], 0, 0, 0);
    }
  }
  // epilogue: hdn = tanh(z1+b1); z2 = hdn@W2+b2; softmax; store
  float pz[4][3];
  #pragma unroll
  for (int r=0;r<4;r++){ pz[r][0]=0.f; pz[r][1]=0.f; pz[r][2]=0.f; }
  #pragma unroll
  for (int nt=0;nt<20;nt++){
    int n = nt*16 + col;
    if (n < 300){
      float bb = b1[n];
      float w20 = W2[n*3+0], w21 = W2[n*3+1], w22 = W2[n*3+2];
      #pragma unroll
      for (int r=0;r<4;r++){
        float hdn = tanh_f(acc[nt][r] + bb);
        pz[r][0] = fmaf(hdn, w20, pz[r][0]);
        pz[r][1] = fmaf(hdn, w21, pz[r][1]);
        pz[r][2] = fmaf(hdn, w22, pz[r][2]);
      }
    }
  }
  #pragma unroll
  for (int off=1; off<16; off<<=1){
    #pragma unroll
    for (int r=0;r<4;r++){
      pz[r][0] += __shfl_xor(pz[r][0], off, 64);
      pz[r][1] += __shfl_xor(pz[r][1], off, 64);
      pz[r][2] += __shfl_xor(pz[r][2], off, 64);
    }
  }
  float c0 = b2[0], c1 = b2[1], c2 = b2[2];
  #pragma unroll
  for (int r=0;r<4;r++){
    float z0 = pz[r][0]+c0, z1 = pz[r][1]+c1, z2 = pz[r][2]+c2;
    float mx = fmaxf(z0, fmaxf(z1, z2));
    float e0 = __expf(z0-mx), e1 = __expf(z1-mx), e2 = __expf(z2-mx);
    float inv = 1.0f/(e0+e1+e2);
    if (col < 3){
      float pv = (col==0 ? e0 : (col==1 ? e1 : e2)) * inv;
      out[(m0 + w*16 + quad*4 + r)*3 + col] = pv;
    }
  }
}

// ---------- launch ----------
extern "C" void kernel_launch(void* const* d_in, const int* in_sizes, int n_in,
                              void* d_out, int out_size, void* d_ws, size_t ws_size,
                              hipStream_t stream)
{
  const int*   x     = (const int*)  d_in[0];
  const int*   paths = (const int*)  d_in[1];
  const float* emb   = (const float*)d_in[2];
  const float* Wih_f = (const float*)d_in[3];
  const float* Whh_f = (const float*)d_in[4];
  const float* bih_f = (const float*)d_in[5];
  const float* bhh_f = (const float*)d_in[6];
  const float* Wih_b = (const float*)d_in[7];
  const float* Whh_b = (const float*)d_in[8];
  const float* bih_b = (const float*)d_in[9];
  const float* bhh_b = (const float*)d_in[10];
  const float* W1    = (const float*)d_in[11];
  const float* b1    = (const float*)d_in[12];
  const float* W2    = (const float*)d_in[13];
  const float* b2    = (const float*)d_in[14];
  float* out = (float*)d_out;

  char* ws = (char*)d_ws;
  u16*   xe    = (u16*)  (ws + 0);          //  8,388,608 B
  u16*   wc    = (u16*)  (ws + 8388608);    //    212,992 B
  float* biasC = (float*)(ws + 8601600);    //      3,200 B
  float* whhP  = (float*)(ws + 8604800);    //    332,800 B
  u16*   w1b   = (u16*)  (ws + 8937600);    //    430,080 B
  u16*   inp   = (u16*)  (ws + 9367680);    // 52,428,800 B
  u16*   hbt   = (u16*)  (ws + 61796480);   // 14,680,064 B  (total 76,476,544)

  const int prep_total = 32768*128 + 832*128 + 800 + 83200 + 672*320 + 32768*24;
  prep_kernel<<<(prep_total + 255)/256, 256, 0, stream>>>(
      x, emb, Wih_f, Whh_f, bih_f, bhh_f, Wih_b, Whh_b, bih_b, bhh_b, W1,
      xe, wc, biasC, whhP, w1b, hbt);
  gemm1_kernel<<<dim3(512, 13), 256, 0, stream>>>(xe, wc, biasC, inp);
  lstm_kernel<<<512, 832, 0, stream>>>(inp, whhP, hbt);
  mlp_kernel<<<510, 512, 0, stream>>>(hbt, w1b, paths, b1, W2, b2, out);
}

// Round 5
// 500.860 us; speedup vs baseline: 1.0386x; 1.0386x over previous
//
#include <hip/hip_runtime.h>

typedef unsigned short u16;
typedef short short8 __attribute__((ext_vector_type(8)));
typedef float f32x4 __attribute__((ext_vector_type(4)));

// ---------- helpers ----------
__device__ __forceinline__ u16 f2b(float x){
  union{float f; unsigned u;} v; v.f = x;
  unsigned r = (v.u + 0x7FFFu + ((v.u >> 16) & 1u)) >> 16;
  return (u16)r;
}
__device__ __forceinline__ float b2f(u16 h){
  union{unsigned u; float f;} v; v.u = ((unsigned)h) << 16; return v.f;
}
__device__ __forceinline__ float sigm(float x){ return 1.0f/(1.0f + __expf(-x)); }
__device__ __forceinline__ float tanh_f(float x){ return 1.0f - 2.0f/(1.0f + __expf(2.0f*x)); }

// force-VGPR fused multiply-accumulate: "v" constraints pin the vreg class to
// arch VGPR (defeats hipcc's AGPR-parking / scratch-spill of weight arrays,
// measured rounds 0/1/2/4)
#define FMAC_V(acc, w, h) asm("v_fmac_f32 %0, %1, %2" : "+v"(acc) : "v"(w), "v"(h))

// ---------- prep: xe gather->bf16, Wcomb, bias, Whh quad repack, W1 repack, hbt pad zero ----------
__global__ void prep_kernel(const int* __restrict__ x, const float* __restrict__ emb,
   const float* __restrict__ Wih_f, const float* __restrict__ Whh_f,
   const float* __restrict__ bih_f, const float* __restrict__ bhh_f,
   const float* __restrict__ Wih_b, const float* __restrict__ Whh_b,
   const float* __restrict__ bih_b, const float* __restrict__ bhh_b,
   const float* __restrict__ W1,
   u16* __restrict__ xe, u16* __restrict__ wc, float* __restrict__ biasC,
   float* __restrict__ whhQ, u16* __restrict__ w1b, u16* __restrict__ hbt)
{
  int id = blockIdx.x*256 + threadIdx.x;
  const int N0 = 32768*128;   // xe  [p][k]
  const int N1 = 832*128;     // wc  [n][k]
  const int N2 = 800;         // biasC
  const int N3 = 80000;       // whhQ [d][k][p]  p = u*4+g, weight row g*100+u
  const int N4 = 672*320;     // w1b  (id = k*320+n)
  const int N5 = 32768*24;    // hbt pad cols 200..223
  if (id < N0){
    int p = id >> 7, k = id & 127;
    float v = 0.f;
    if (k < 100) v = emb[x[p]*100 + k];
    xe[id] = f2b(v);
    return;
  }
  id -= N0;
  if (id < N1){
    int n = id >> 7, k = id & 127;
    float v = 0.f;
    if (k < 100){
      if (n < 400) v = Wih_f[n*100+k];
      else if (n < 800) v = Wih_b[(n-400)*100+k];
    }
    wc[id] = f2b(v);
    return;
  }
  id -= N1;
  if (id < N2){
    biasC[id] = (id < 400) ? (bih_f[id]+bhh_f[id]) : (bih_b[id-400]+bhh_b[id-400]);
    return;
  }
  id -= N2;
  if (id < N3){
    int d = id / 40000; int rem = id - d*40000; int k = rem / 400; int p = rem - k*400;
    int uu = p >> 2, gg = p & 3;
    const float* W = d ? Whh_b : Whh_f;
    whhQ[id] = W[(gg*100 + uu)*100 + k];
    return;
  }
  id -= N3;
  if (id < N4){
    int k = id / 320; int n = id - k*320;
    int seg = k / 224; int wwk = k - seg*224;
    float v = 0.f;
    if (n < 300 && wwk < 200) v = W1[(seg*200 + wwk)*300 + n];
    w1b[n*672 + k] = f2b(v);
    return;
  }
  id -= N4;
  if (id < N5){
    int p = id / 24; int k = id - p*24;
    hbt[p*224 + 200 + k] = 0;
  }
}

// ---------- GEMM1: inp[d][b][t][u*4+g] = xe @ Wcomb^T + bias, bf16 MFMA ----------
// M=32768 (p=b*128+t), N=832 (pad of 800), K=128 (pad of 100)
// NOTE: store is permuted to the LSTM's quad layout (u*4+g), coalesced for its loads.
__global__ __launch_bounds__(256) void gemm1_kernel(const u16* __restrict__ xe,
    const u16* __restrict__ wc, const float* __restrict__ biasC, u16* __restrict__ inp)
{
  __shared__ __align__(16) u16 As[64*136];   // stride 136: 2-way bank alias only
  __shared__ __align__(16) u16 Bs[64*136];
  const int m0 = blockIdx.x*64, n0 = blockIdx.y*64;
  const int tid = threadIdx.x;
  #pragma unroll
  for (int i=0;i<4;i++){
    int f = i*256 + tid;
    int row = f >> 4, c8 = f & 15;
    *(uint4*)&As[row*136 + c8*8] = *(const uint4*)&xe[(m0+row)*128 + c8*8];
    *(uint4*)&Bs[row*136 + c8*8] = *(const uint4*)&wc[(n0+row)*128 + c8*8];
  }
  __syncthreads();
  const int w = tid >> 6, lane = tid & 63, col = lane & 15, quad = lane >> 4;
  f32x4 acc[4];
  #pragma unroll
  for (int nt=0;nt<4;nt++) acc[nt] = (f32x4){0.f,0.f,0.f,0.f};
  #pragma unroll
  for (int kc=0;kc<4;kc++){
    short8 af = *(const short8*)&As[(w*16+col)*136 + kc*32 + quad*8];
    #pragma unroll
    for (int nt=0;nt<4;nt++){
      short8 bfrag = *(const short8*)&Bs[(nt*16+col)*136 + kc*32 + quad*8];
      acc[nt] = __builtin_amdgcn_mfma_f32_16x16x32_bf16(af, bfrag, acc[nt], 0, 0, 0);
    }
  }
  #pragma unroll
  for (int nt=0;nt<4;nt++){
    int n = n0 + nt*16 + col;
    if (n < 800){
      float bs = biasC[n];
      int dir = (n >= 400) ? 1 : 0;
      int j = n - dir*400;
      int gg = j / 100, uu = j - gg*100;
      int pj = uu*4 + gg;
      #pragma unroll
      for (int r=0;r<4;r++){
        int m = m0 + w*16 + quad*4 + r;
        inp[(dir*32768 + m)*400 + pj] = f2b(acc[nt][r] + bs);
      }
    }
  }
}

// ---------- LSTM recurrence: 512 chains (dir,b), one block each ----------
// tid -> (u = tid>>2, g = tid&3): a unit's 4 gates live in one quad.
// Per step: 25 uniform (broadcast) ds_read_b128 of h, 100 asm v_fmac (weights
// pinned to arch VGPRs by "v" constraints), 3 intra-quad shfl_xor to gather
// i/f/g/o, cell update computed redundantly in all 4 lanes. ONE barrier/step;
// h double-buffered by parity.
__global__ __launch_bounds__(448, 2) void lstm_kernel(const u16* __restrict__ inp,
    const float* __restrict__ whhQ, u16* __restrict__ hbt)
{
  __shared__ __align__(16) float hs2[2][104];
  const int cid = blockIdx.x;
  const int b = cid & 255, dir = cid >> 8;
  const int tid = threadIdx.x;
  const int u = tid >> 2, g = tid & 3;
  if (tid < 104) hs2[0][tid] = 0.f;

  float whh[100];
  const u16* ipt = inp;
  u16* hpt = hbt;
  u16 cur = 0;
  float c = 0.f;
  const int t0 = dir ? 127 : 0;
  const int dIp = dir ? -400 : 400;
  const int dHp = dir ? -224 : 224;
  if (tid < 400){
    const float* wp = whhQ + dir*40000 + tid;   // [d][k][p], coalesced over p
    #pragma unroll
    for (int k=0;k<100;k++) whh[k] = wp[k*400];
    ipt = inp + ((size_t)(dir*32768 + b*128 + t0))*400 + tid;
    hpt = hbt + ((size_t)(b*128 + t0))*224 + dir*100 + u;
    cur = *ipt;            // 1-deep pipeline on the preactivation load
  }
  __syncthreads();

  const bool g1 = (g & 1) != 0, g2 = (g & 2) != 0;
  for (int step=0; step<128; step++){
    const int par = step & 1;
    if (tid < 400){
      float pre0 = b2f(cur);
      if (step < 127) cur = ipt[dIp];
      ipt += dIp;
      const float4* h4 = (const float4*)&hs2[par][0];   // uniform -> broadcast
      float a0=0.f,a1=0.f,a2=0.f,a3=0.f;
      #pragma unroll
      for (int kk=0;kk<25;kk++){
        float4 hv = h4[kk];
        FMAC_V(a0, whh[4*kk+0], hv.x);
        FMAC_V(a1, whh[4*kk+1], hv.y);
        FMAC_V(a2, whh[4*kk+2], hv.z);
        FMAC_V(a3, whh[4*kk+3], hv.w);
      }
      float pre = pre0 + ((a0+a1)+(a2+a3));
      // quad gather: lane holding gate g also gets g^1, g^2, g^3
      float s1 = __shfl_xor(pre, 1, 64);
      float t2 = __shfl_xor(pre, 2, 64);
      float t3 = __shfl_xor(s1, 2, 64);
      float iv = g2 ? (g1 ? t3 : t2) : (g1 ? s1 : pre);
      float fv = g2 ? (g1 ? t2 : t3) : (g1 ? pre : s1);
      float gv = g2 ? (g1 ? s1 : pre) : (g1 ? t3 : t2);
      float ov = g2 ? (g1 ? pre : s1) : (g1 ? t2 : t3);
      c = sigm(fv)*c + sigm(iv)*tanh_f(gv);
      float h = sigm(ov)*tanh_f(c);
      if (g == 0)      hs2[par^1][u] = h;
      else if (g == 1) *hpt = f2b(h);
      hpt += dHp;
    }
    __syncthreads();
  }
}

// ---------- MLP: gathered bf16 MFMA GEMM + tanh + W2 + softmax fused ----------
// M=65280 (m=b*255+c), N=320 (pad of 300), K=672 (3 segments of 224, valid 200)
__global__ __launch_bounds__(512) void mlp_kernel(const u16* __restrict__ hbt,
    const u16* __restrict__ w1b, const int* __restrict__ paths,
    const float* __restrict__ b1, const float* __restrict__ W2,
    const float* __restrict__ b2, float* __restrict__ out)
{
  __shared__ __align__(16) u16 As[128*40];   // stride 40: 2-way alias only
  __shared__ __align__(16) u16 Bs[320*40];
  const int m0 = blockIdx.x*128;
  const int tid = threadIdx.x;
  const int arow = tid >> 2, ac8 = tid & 3;
  const int am = m0 + arow;
  const int ab = am / 255;   // batch index of this A row
  const int w = tid >> 6, lane = tid & 63, col = lane & 15, quad = lane >> 4;
  f32x4 acc[20];
  #pragma unroll
  for (int nt=0;nt<20;nt++) acc[nt] = (f32x4){0.f,0.f,0.f,0.f};
  for (int kc=0;kc<21;kc++){
    __syncthreads();
    // stage W1 chunk: 320 rows x 32 k
    for (int f = tid; f < 1280; f += 512){
      int br = f >> 2, bc = f & 3;
      *(uint4*)&Bs[br*40 + bc*8] = *(const uint4*)&w1b[br*672 + kc*32 + bc*8];
    }
    // stage gathered A chunk: 128 rows x 32 k (one 16B piece per thread)
    int seg = (kc >= 14) ? 2 : (kc >= 7 ? 1 : 0);
    int ko = kc - seg*7;
    int it = paths[am*3 + seg];
    uint4 v = make_uint4(0u,0u,0u,0u);
    if (it >= 0){
      int t = it > 127 ? 127 : it;
      v = *(const uint4*)&hbt[(ab*128 + t)*224 + ko*32 + ac8*8];
    }
    *(uint4*)&As[arow*40 + ac8*8] = v;
    __syncthreads();
    short8 af = *(const short8*)&As[(w*16+col)*40 + quad*8];
    #pragma unroll
    for (int nt=0;nt<20;nt++){
      short8 bfrag = *(const short8*)&Bs[(nt*16+col)*40 + quad*8];
      acc[nt] = __builtin_amdgcn_mfma_f32_16x16x32_bf16(af, bfrag, acc[nt], 0, 0, 0);
    }
  }
  // epilogue: hdn = tanh(z1+b1); z2 = hdn@W2+b2; softmax; store
  float pz[4][3];
  #pragma unroll
  for (int r=0;r<4;r++){ pz[r][0]=0.f; pz[r][1]=0.f; pz[r][2]=0.f; }
  #pragma unroll
  for (int nt=0;nt<20;nt++){
    int n = nt*16 + col;
    if (n < 300){
      float bb = b1[n];
      float w20 = W2[n*3+0], w21 = W2[n*3+1], w22 = W2[n*3+2];
      #pragma unroll
      for (int r=0;r<4;r++){
        float hdn = tanh_f(acc[nt][r] + bb);
        pz[r][0] = fmaf(hdn, w20, pz[r][0]);
        pz[r][1] = fmaf(hdn, w21, pz[r][1]);
        pz[r][2] = fmaf(hdn, w22, pz[r][2]);
      }
    }
  }
  #pragma unroll
  for (int off=1; off<16; off<<=1){
    #pragma unroll
    for (int r=0;r<4;r++){
      pz[r][0] += __shfl_xor(pz[r][0], off, 64);
      pz[r][1] += __shfl_xor(pz[r][1], off, 64);
      pz[r][2] += __shfl_xor(pz[r][2], off, 64);
    }
  }
  float c0 = b2[0], c1 = b2[1], c2 = b2[2];
  #pragma unroll
  for (int r=0;r<4;r++){
    float z0 = pz[r][0]+c0, z1 = pz[r][1]+c1, z2 = pz[r][2]+c2;
    float mx = fmaxf(z0, fmaxf(z1, z2));
    float e0 = __expf(z0-mx), e1 = __expf(z1-mx), e2 = __expf(z2-mx);
    float inv = 1.0f/(e0+e1+e2);
    if (col < 3){
      float pv = (col==0 ? e0 : (col==1 ? e1 : e2)) * inv;
      out[(m0 + w*16 + quad*4 + r)*3 + col] = pv;
    }
  }
}

// ---------- launch ----------
extern "C" void kernel_launch(void* const* d_in, const int* in_sizes, int n_in,
                              void* d_out, int out_size, void* d_ws, size_t ws_size,
                              hipStream_t stream)
{
  const int*   x     = (const int*)  d_in[0];
  const int*   paths = (const int*)  d_in[1];
  const float* emb   = (const float*)d_in[2];
  const float* Wih_f = (const float*)d_in[3];
  const float* Whh_f = (const float*)d_in[4];
  const float* bih_f = (const float*)d_in[5];
  const float* bhh_f = (const float*)d_in[6];
  const float* Wih_b = (const float*)d_in[7];
  const float* Whh_b = (const float*)d_in[8];
  const float* bih_b = (const float*)d_in[9];
  const float* bhh_b = (const float*)d_in[10];
  const float* W1    = (const float*)d_in[11];
  const float* b1    = (const float*)d_in[12];
  const float* W2    = (const float*)d_in[13];
  const float* b2    = (const float*)d_in[14];
  float* out = (float*)d_out;

  char* ws = (char*)d_ws;
  u16*   xe    = (u16*)  (ws + 0);          //  8,388,608 B
  u16*   wc    = (u16*)  (ws + 8388608);    //    212,992 B
  float* biasC = (float*)(ws + 8601600);    //      3,200 B
  float* whhQ  = (float*)(ws + 8604800);    //    320,000 B
  u16*   w1b   = (u16*)  (ws + 8924800);    //    430,080 B
  u16*   inp   = (u16*)  (ws + 9354880);    // 52,428,800 B
  u16*   hbt   = (u16*)  (ws + 61783680);   // 14,680,064 B  (total 76,463,744)

  const int prep_total = 32768*128 + 832*128 + 800 + 80000 + 672*320 + 32768*24;
  prep_kernel<<<(prep_total + 255)/256, 256, 0, stream>>>(
      x, emb, Wih_f, Whh_f, bih_f, bhh_f, Wih_b, Whh_b, bih_b, bhh_b, W1,
      xe, wc, biasC, whhQ, w1b, hbt);
  gemm1_kernel<<<dim3(512, 13), 256, 0, stream>>>(xe, wc, biasC, inp);
  lstm_kernel<<<512, 448, 0, stream>>>(inp, whhQ, hbt);
  mlp_kernel<<<510, 512, 0, stream>>>(hbt, w1b, paths, b1, W2, b2, out);
}

// Round 6
// 418.085 us; speedup vs baseline: 1.2442x; 1.1980x over previous
//
#include <hip/hip_runtime.h>

typedef unsigned short u16;
typedef short short8 __attribute__((ext_vector_type(8)));
typedef float f32x4 __attribute__((ext_vector_type(4)));

// ---------- helpers ----------
__device__ __forceinline__ u16 f2b(float x){
  union{float f; unsigned u;} v; v.f = x;
  unsigned r = (v.u + 0x7FFFu + ((v.u >> 16) & 1u)) >> 16;
  return (u16)r;
}
__device__ __forceinline__ float b2f(u16 h){
  union{unsigned u; float f;} v; v.u = ((unsigned)h) << 16; return v.f;
}
__device__ __forceinline__ float sigm(float x){ return 1.0f/(1.0f + __expf(-x)); }
__device__ __forceinline__ float tanh_f(float x){ return 1.0f - 2.0f/(1.0f + __expf(2.0f*x)); }

// ---------- prep: xe gather->bf16, Wcomb, bias, Whh row-contiguous quad repack, W1 repack, hbt pad ----------
__global__ void prep_kernel(const int* __restrict__ x, const float* __restrict__ emb,
   const float* __restrict__ Wih_f, const float* __restrict__ Whh_f,
   const float* __restrict__ bih_f, const float* __restrict__ bhh_f,
   const float* __restrict__ Wih_b, const float* __restrict__ Whh_b,
   const float* __restrict__ bih_b, const float* __restrict__ bhh_b,
   const float* __restrict__ W1,
   u16* __restrict__ xe, u16* __restrict__ wc, float* __restrict__ biasC,
   float* __restrict__ whhR, u16* __restrict__ w1b, u16* __restrict__ hbt)
{
  int id = blockIdx.x*256 + threadIdx.x;
  const int N0 = 32768*128;   // xe  [p][k]
  const int N1 = 832*128;     // wc  [n][k]
  const int N2 = 800;         // biasC
  const int N3 = 80000;       // whhR [d][p][k]  p = u*4+g, row g*100+u, k contiguous
  const int N4 = 672*320;     // w1b  (id = k*320+n)
  const int N5 = 32768*24;    // hbt pad cols 200..223
  if (id < N0){
    int p = id >> 7, k = id & 127;
    float v = 0.f;
    if (k < 100) v = emb[x[p]*100 + k];
    xe[id] = f2b(v);
    return;
  }
  id -= N0;
  if (id < N1){
    int n = id >> 7, k = id & 127;
    float v = 0.f;
    if (k < 100){
      if (n < 400) v = Wih_f[n*100+k];
      else if (n < 800) v = Wih_b[(n-400)*100+k];
    }
    wc[id] = f2b(v);
    return;
  }
  id -= N1;
  if (id < N2){
    biasC[id] = (id < 400) ? (bih_f[id]+bhh_f[id]) : (bih_b[id-400]+bhh_b[id-400]);
    return;
  }
  id -= N2;
  if (id < N3){
    int d = id / 40000; int rem = id - d*40000; int p = rem / 100; int k = rem - p*100;
    int uu = p >> 2, gg = p & 3;
    const float* W = d ? Whh_b : Whh_f;
    whhR[id] = W[(gg*100 + uu)*100 + k];
    return;
  }
  id -= N3;
  if (id < N4){
    int k = id / 320; int n = id - k*320;
    int seg = k / 224; int wwk = k - seg*224;
    float v = 0.f;
    if (n < 300 && wwk < 200) v = W1[(seg*200 + wwk)*300 + n];
    w1b[n*672 + k] = f2b(v);
    return;
  }
  id -= N4;
  if (id < N5){
    int p = id / 24; int k = id - p*24;
    hbt[p*224 + 200 + k] = 0;
  }
}

// ---------- GEMM1: inp[d][b][t][u*4+g] = xe @ Wcomb^T + bias, bf16 MFMA ----------
__global__ __launch_bounds__(256) void gemm1_kernel(const u16* __restrict__ xe,
    const u16* __restrict__ wc, const float* __restrict__ biasC, u16* __restrict__ inp)
{
  __shared__ __align__(16) u16 As[64*136];
  __shared__ __align__(16) u16 Bs[64*136];
  const int m0 = blockIdx.x*64, n0 = blockIdx.y*64;
  const int tid = threadIdx.x;
  #pragma unroll
  for (int i=0;i<4;i++){
    int f = i*256 + tid;
    int row = f >> 4, c8 = f & 15;
    *(uint4*)&As[row*136 + c8*8] = *(const uint4*)&xe[(m0+row)*128 + c8*8];
    *(uint4*)&Bs[row*136 + c8*8] = *(const uint4*)&wc[(n0+row)*128 + c8*8];
  }
  __syncthreads();
  const int w = tid >> 6, lane = tid & 63, col = lane & 15, quad = lane >> 4;
  f32x4 acc[4];
  #pragma unroll
  for (int nt=0;nt<4;nt++) acc[nt] = (f32x4){0.f,0.f,0.f,0.f};
  #pragma unroll
  for (int kc=0;kc<4;kc++){
    short8 af = *(const short8*)&As[(w*16+col)*136 + kc*32 + quad*8];
    #pragma unroll
    for (int nt=0;nt<4;nt++){
      short8 bfrag = *(const short8*)&Bs[(nt*16+col)*136 + kc*32 + quad*8];
      acc[nt] = __builtin_amdgcn_mfma_f32_16x16x32_bf16(af, bfrag, acc[nt], 0, 0, 0);
    }
  }
  #pragma unroll
  for (int nt=0;nt<4;nt++){
    int n = n0 + nt*16 + col;
    if (n < 800){
      float bs = biasC[n];
      int dir = (n >= 400) ? 1 : 0;
      int j = n - dir*400;
      int gg = j / 100, uu = j - gg*100;
      int pj = uu*4 + gg;
      #pragma unroll
      for (int r=0;r<4;r++){
        int m = m0 + w*16 + quad*4 + r;
        inp[(dir*32768 + m)*400 + pj] = f2b(acc[nt][r] + bs);
      }
    }
  }
}

// ---------- LSTM recurrence: full-asm inner loop, weights in clobber-reserved VGPRs ----------
// 512 chains, 1 block each, 448 threads; tid -> (u = tid>>2, gate g = tid&3).
// Weights v40-v139 (100 fp32, loaded once). Per step: prefetched inp load,
// 25 broadcast ds_read_b128 (4-deep pipelined, counted lgkmcnt), 100 v_fmac,
// quad gather via ds_swizzle + cndmask (masks precomputed by ballot),
// exp/rcp activations, exec-masked h(LDS)/hbt stores, one s_barrier.
#define DG(W0,W1,W2,W3,S0,S1,S2,S3,OFF) \
  "s_waitcnt lgkmcnt(3)\n\t" \
  "v_fmac_f32 v16, v" #W0 ", v" #S0 "\n\t" \
  "v_fmac_f32 v17, v" #W1 ", v" #S1 "\n\t" \
  "v_fmac_f32 v18, v" #W2 ", v" #S2 "\n\t" \
  "v_fmac_f32 v19, v" #W3 ", v" #S3 "\n\t" \
  "ds_read_b128 v[" #S0 ":" #S3 "], v30 offset:" #OFF "\n\t"
#define DGT(W0,W1,W2,W3,S0,S1,S2,S3,CNT) \
  "s_waitcnt lgkmcnt(" #CNT ")\n\t" \
  "v_fmac_f32 v16, v" #W0 ", v" #S0 "\n\t" \
  "v_fmac_f32 v17, v" #W1 ", v" #S1 "\n\t" \
  "v_fmac_f32 v18, v" #W2 ", v" #S2 "\n\t" \
  "v_fmac_f32 v19, v" #W3 ", v" #S3 "\n\t"

__global__ __launch_bounds__(448) void lstm_kernel(const u16* __restrict__ inp,
    const float* __restrict__ whhR, u16* __restrict__ hbt)
{
  __shared__ __align__(16) float hs2[2][128];
  const int cid = blockIdx.x;
  const int b = cid & 255, dir = cid >> 8;
  const int tid = threadIdx.x;
  for (int i = tid; i < 256; i += 448) ((float*)hs2)[i] = 0.f;
  __syncthreads();
  if (tid < 400){
    const int u = tid >> 2, g = tid & 3;
    unsigned long long fe  = __ballot(1);
    unsigned long long g0e = __ballot(g == 0);
    unsigned long long g1e = __ballot(g == 1);
    unsigned long long g1m = __ballot((g & 1) != 0);
    unsigned long long g2m = __ballot((g & 2) != 0);
    const int t0 = dir ? 127 : 0;
    const int dIb = dir ? -800 : 800;     // inp byte stride per step
    const int dHb = dir ? -448 : 448;     // hbt byte stride per step
    unsigned ra = (unsigned)(size_t)&hs2[0][0];          // LDS byte offset (aperture low32)
    unsigned ha = ra + 512u + 4u*(unsigned)u;            // write buf = hs2[1] first
    unsigned wo = (unsigned)(dir*40000 + tid*100) * 4u;
    unsigned io = (unsigned)((dir*32768 + b*128 + t0)*400 + tid) * 2u;
    unsigned ho = (unsigned)((b*128 + t0)*224 + dir*100 + u) * 2u;
    asm volatile(
      // ---- prologue ----
      "v_mov_b32 v30, %[ra]\n\t"
      "v_mov_b32 v31, %[ha]\n\t"
      "v_mov_b32 v32, %[ho]\n\t"
      "v_mov_b32 v33, %[io]\n\t"
      "v_mov_b32 v38, 0\n\t"
      "s_mov_b32 s20, 128\n\t"
      "global_load_ushort v37, v33, %[ib]\n\t"
      "v_add_u32 v33, %[dis], v33\n\t"
      "global_load_dwordx4 v[40:43],   %[wo], %[wb]\n\t"
      "global_load_dwordx4 v[44:47],   %[wo], %[wb] offset:16\n\t"
      "global_load_dwordx4 v[48:51],   %[wo], %[wb] offset:32\n\t"
      "global_load_dwordx4 v[52:55],   %[wo], %[wb] offset:48\n\t"
      "global_load_dwordx4 v[56:59],   %[wo], %[wb] offset:64\n\t"
      "global_load_dwordx4 v[60:63],   %[wo], %[wb] offset:80\n\t"
      "global_load_dwordx4 v[64:67],   %[wo], %[wb] offset:96\n\t"
      "global_load_dwordx4 v[68:71],   %[wo], %[wb] offset:112\n\t"
      "global_load_dwordx4 v[72:75],   %[wo], %[wb] offset:128\n\t"
      "global_load_dwordx4 v[76:79],   %[wo], %[wb] offset:144\n\t"
      "global_load_dwordx4 v[80:83],   %[wo], %[wb] offset:160\n\t"
      "global_load_dwordx4 v[84:87],   %[wo], %[wb] offset:176\n\t"
      "global_load_dwordx4 v[88:91],   %[wo], %[wb] offset:192\n\t"
      "global_load_dwordx4 v[92:95],   %[wo], %[wb] offset:208\n\t"
      "global_load_dwordx4 v[96:99],   %[wo], %[wb] offset:224\n\t"
      "global_load_dwordx4 v[100:103], %[wo], %[wb] offset:240\n\t"
      "global_load_dwordx4 v[104:107], %[wo], %[wb] offset:256\n\t"
      "global_load_dwordx4 v[108:111], %[wo], %[wb] offset:272\n\t"
      "global_load_dwordx4 v[112:115], %[wo], %[wb] offset:288\n\t"
      "global_load_dwordx4 v[116:119], %[wo], %[wb] offset:304\n\t"
      "global_load_dwordx4 v[120:123], %[wo], %[wb] offset:320\n\t"
      "global_load_dwordx4 v[124:127], %[wo], %[wb] offset:336\n\t"
      "global_load_dwordx4 v[128:131], %[wo], %[wb] offset:352\n\t"
      "global_load_dwordx4 v[132:135], %[wo], %[wb] offset:368\n\t"
      "global_load_dwordx4 v[136:139], %[wo], %[wb] offset:384\n\t"
      "s_waitcnt vmcnt(0)\n\t"
      "LSTM_T%=:\n\t"
      // inp 1-step prefetch: cur <= nxt (nxt guaranteed done), issue next
      "s_waitcnt vmcnt(0)\n\t"
      "v_mov_b32 v36, v37\n\t"
      "global_load_ushort v37, v33, %[ib]\n\t"
      "v_add_u32 v33, %[dis], v33\n\t"
      // h dot: 4-slot pipelined broadcast reads + 100 fmac into v16-v19
      "ds_read_b128 v[0:3], v30\n\t"
      "ds_read_b128 v[4:7], v30 offset:16\n\t"
      "ds_read_b128 v[8:11], v30 offset:32\n\t"
      "ds_read_b128 v[12:15], v30 offset:48\n\t"
      "v_mov_b32 v16, 0\n\t"
      "v_mov_b32 v17, 0\n\t"
      "v_mov_b32 v18, 0\n\t"
      "v_mov_b32 v19, 0\n\t"
      DG(40,41,42,43,   0,1,2,3,    64)
      DG(44,45,46,47,   4,5,6,7,    80)
      DG(48,49,50,51,   8,9,10,11,  96)
      DG(52,53,54,55,   12,13,14,15,112)
      DG(56,57,58,59,   0,1,2,3,    128)
      DG(60,61,62,63,   4,5,6,7,    144)
      DG(64,65,66,67,   8,9,10,11,  160)
      DG(68,69,70,71,   12,13,14,15,176)
      DG(72,73,74,75,   0,1,2,3,    192)
      DG(76,77,78,79,   4,5,6,7,    208)
      DG(80,81,82,83,   8,9,10,11,  224)
      DG(84,85,86,87,   12,13,14,15,240)
      DG(88,89,90,91,   0,1,2,3,    256)
      DG(92,93,94,95,   4,5,6,7,    272)
      DG(96,97,98,99,   8,9,10,11,  288)
      DG(100,101,102,103, 12,13,14,15,304)
      DG(104,105,106,107, 0,1,2,3,    320)
      DG(108,109,110,111, 4,5,6,7,    336)
      DG(112,113,114,115, 8,9,10,11,  352)
      DG(116,117,118,119, 12,13,14,15,368)
      DG(120,121,122,123, 0,1,2,3,    384)
      DGT(124,125,126,127, 4,5,6,7,   3)
      DGT(128,129,130,131, 8,9,10,11, 2)
      DGT(132,133,134,135, 12,13,14,15,1)
      DGT(136,137,138,139, 0,1,2,3,   0)
      "v_add_f32 v16, v16, v17\n\t"
      "v_add_f32 v18, v18, v19\n\t"
      "v_add_f32 v16, v16, v18\n\t"
      "v_lshlrev_b32 v24, 16, v36\n\t"
      "v_add_f32 v16, v16, v24\n\t"            // pre
      // quad gather: s1 = xor1, t2 = xor2, t3 = xor2(s1)
      "ds_swizzle_b32 v25, v16 offset:0x041f\n\t"
      "ds_swizzle_b32 v26, v16 offset:0x081f\n\t"
      "s_waitcnt lgkmcnt(0)\n\t"
      "ds_swizzle_b32 v27, v25 offset:0x081f\n\t"
      "s_waitcnt lgkmcnt(0)\n\t"
      "v_cndmask_b32 v28, v16, v25, %[g1m]\n\t" // A = g1? s1 : pre
      "v_cndmask_b32 v29, v26, v27, %[g1m]\n\t" // B = g1? t3 : t2
      "v_cndmask_b32 v20, v28, v29, %[g2m]\n\t" // iv
      "v_cndmask_b32 v22, v29, v28, %[g2m]\n\t" // gv
      "v_cndmask_b32 v24, v25, v16, %[g1m]\n\t" // C = g1? pre : s1
      "v_cndmask_b32 v25, v27, v26, %[g1m]\n\t" // D = g1? t2 : t3
      "v_cndmask_b32 v21, v24, v25, %[g2m]\n\t" // fv
      "v_cndmask_b32 v23, v25, v24, %[g2m]\n\t" // ov
      // activations: sigm(x)=1/(1+2^(-x*log2e)); tanh(x)=1-2/(1+2^(x*2log2e))
      "v_mul_f32 v24, 0xbfb8aa3b, v21\n\t"
      "v_mul_f32 v25, 0xbfb8aa3b, v20\n\t"
      "v_mul_f32 v26, 0x4038aa3b, v22\n\t"
      "v_exp_f32 v24, v24\n\t"
      "v_exp_f32 v25, v25\n\t"
      "v_exp_f32 v26, v26\n\t"
      "v_add_f32 v24, 1.0, v24\n\t"
      "v_add_f32 v25, 1.0, v25\n\t"
      "v_add_f32 v26, 1.0, v26\n\t"
      "v_rcp_f32 v24, v24\n\t"                 // sf
      "v_rcp_f32 v25, v25\n\t"                 // si
      "v_rcp_f32 v26, v26\n\t"
      "v_mov_b32 v27, 1.0\n\t"
      "v_fmac_f32 v27, -2.0, v26\n\t"          // tg = tanh(gv)
      "v_mul_f32 v25, v25, v27\n\t"            // si*tg
      "v_fmac_f32 v25, v24, v38\n\t"           // + sf*c
      "v_mov_b32 v38, v25\n\t"                 // c
      "v_mul_f32 v24, 0x4038aa3b, v38\n\t"
      "v_mul_f32 v26, 0xbfb8aa3b, v23\n\t"
      "v_exp_f32 v24, v24\n\t"
      "v_exp_f32 v26, v26\n\t"
      "v_add_f32 v24, 1.0, v24\n\t"
      "v_add_f32 v26, 1.0, v26\n\t"
      "v_rcp_f32 v24, v24\n\t"
      "v_rcp_f32 v26, v26\n\t"                 // so
      "v_mov_b32 v27, 1.0\n\t"
      "v_fmac_f32 v27, -2.0, v24\n\t"          // tc = tanh(c)
      "v_mul_f32 v28, v26, v27\n\t"            // h
      "v_cvt_pk_bf16_f32 v39, v28, v28\n\t"
      // exec-masked stores: h -> LDS (g==0 lanes), h_bf16 -> hbt (g==1 lanes)
      "s_mov_b64 exec, %[g0e]\n\t"
      "ds_write_b32 v31, v28\n\t"
      "s_mov_b64 exec, %[g1e]\n\t"
      "global_store_short v32, v39, %[hb]\n\t"
      "s_mov_b64 exec, %[fe]\n\t"
      "v_add_u32 v32, %[dhs], v32\n\t"
      "v_xor_b32 v30, 0x200, v30\n\t"
      "v_xor_b32 v31, 0x200, v31\n\t"
      "s_waitcnt lgkmcnt(0)\n\t"
      "s_barrier\n\t"
      "s_sub_u32 s20, s20, 1\n\t"
      "s_cmp_lg_u32 s20, 0\n\t"
      "s_cbranch_scc1 LSTM_T%=\n\t"
      :
      : [ra]"v"(ra), [ha]"v"(ha), [ho]"v"(ho), [io]"v"(io), [wo]"v"(wo),
        [wb]"s"(whhR), [ib]"s"(inp), [hb]"s"(hbt),
        [dis]"s"(dIb), [dhs]"s"(dHb),
        [fe]"s"(fe), [g0e]"s"(g0e), [g1e]"s"(g1e), [g1m]"s"(g1m), [g2m]"s"(g2m)
      : "memory","scc","s20","s21",
        "v0","v1","v2","v3","v4","v5","v6","v7","v8","v9",
        "v10","v11","v12","v13","v14","v15","v16","v17","v18","v19",
        "v20","v21","v22","v23","v24","v25","v26","v27","v28","v29",
        "v30","v31","v32","v33","v34","v35","v36","v37","v38","v39",
        "v40","v41","v42","v43","v44","v45","v46","v47","v48","v49",
        "v50","v51","v52","v53","v54","v55","v56","v57","v58","v59",
        "v60","v61","v62","v63","v64","v65","v66","v67","v68","v69",
        "v70","v71","v72","v73","v74","v75","v76","v77","v78","v79",
        "v80","v81","v82","v83","v84","v85","v86","v87","v88","v89",
        "v90","v91","v92","v93","v94","v95","v96","v97","v98","v99",
        "v100","v101","v102","v103","v104","v105","v106","v107","v108","v109",
        "v110","v111","v112","v113","v114","v115","v116","v117","v118","v119",
        "v120","v121","v122","v123","v124","v125","v126","v127","v128","v129",
        "v130","v131","v132","v133","v134","v135","v136","v137","v138","v139"
    );
  }
}

// ---------- MLP: gathered bf16 MFMA GEMM + tanh + W2 + softmax fused ----------
__global__ __launch_bounds__(512) void mlp_kernel(const u16* __restrict__ hbt,
    const u16* __restrict__ w1b, const int* __restrict__ paths,
    const float* __restrict__ b1, const float* __restrict__ W2,
    const float* __restrict__ b2, float* __restrict__ out)
{
  __shared__ __align__(16) u16 As[128*40];
  __shared__ __align__(16) u16 Bs[320*40];
  const int m0 = blockIdx.x*128;
  const int tid = threadIdx.x;
  const int arow = tid >> 2, ac8 = tid & 3;
  const int am = m0 + arow;
  const int ab = am / 255;
  const int w = tid >> 6, lane = tid & 63, col = lane & 15, quad = lane >> 4;
  f32x4 acc[20];
  #pragma unroll
  for (int nt=0;nt<20;nt++) acc[nt] = (f32x4){0.f,0.f,0.f,0.f};
  for (int kc=0;kc<21;kc++){
    __syncthreads();
    for (int f = tid; f < 1280; f += 512){
      int br = f >> 2, bc = f & 3;
      *(uint4*)&Bs[br*40 + bc*8] = *(const uint4*)&w1b[br*672 + kc*32 + bc*8];
    }
    int seg = (kc >= 14) ? 2 : (kc >= 7 ? 1 : 0);
    int ko = kc - seg*7;
    int it = paths[am*3 + seg];
    uint4 v = make_uint4(0u,0u,0u,0u);
    if (it >= 0){
      int t = it > 127 ? 127 : it;
      v = *(const uint4*)&hbt[(ab*128 + t)*224 + ko*32 + ac8*8];
    }
    *(uint4*)&As[arow*40 + ac8*8] = v;
    __syncthreads();
    short8 af = *(const short8*)&As[(w*16+col)*40 + quad*8];
    #pragma unroll
    for (int nt=0;nt<20;nt++){
      short8 bfrag = *(const short8*)&Bs[(nt*16+col)*40 + quad*8];
      acc[nt] = __builtin_amdgcn_mfma_f32_16x16x32_bf16(af, bfrag, acc[nt], 0, 0, 0);
    }
  }
  float pz[4][3];
  #pragma unroll
  for (int r=0;r<4;r++){ pz[r][0]=0.f; pz[r][1]=0.f; pz[r][2]=0.f; }
  #pragma unroll
  for (int nt=0;nt<20;nt++){
    int n = nt*16 + col;
    if (n < 300){
      float bb = b1[n];
      float w20 = W2[n*3+0], w21 = W2[n*3+1], w22 = W2[n*3+2];
      #pragma unroll
      for (int r=0;r<4;r++){
        float hdn = tanh_f(acc[nt][r] + bb);
        pz[r][0] = fmaf(hdn, w20, pz[r][0]);
        pz[r][1] = fmaf(hdn, w21, pz[r][1]);
        pz[r][2] = fmaf(hdn, w22, pz[r][2]);
      }
    }
  }
  #pragma unroll
  for (int off=1; off<16; off<<=1){
    #pragma unroll
    for (int r=0;r<4;r++){
      pz[r][0] += __shfl_xor(pz[r][0], off, 64);
      pz[r][1] += __shfl_xor(pz[r][1], off, 64);
      pz[r][2] += __shfl_xor(pz[r][2], off, 64);
    }
  }
  float c0 = b2[0], c1 = b2[1], c2 = b2[2];
  #pragma unroll
  for (int r=0;r<4;r++){
    float z0 = pz[r][0]+c0, z1 = pz[r][1]+c1, z2 = pz[r][2]+c2;
    float mx = fmaxf(z0, fmaxf(z1, z2));
    float e0 = __expf(z0-mx), e1 = __expf(z1-mx), e2 = __expf(z2-mx);
    float inv = 1.0f/(e0+e1+e2);
    if (col < 3){
      float pv = (col==0 ? e0 : (col==1 ? e1 : e2)) * inv;
      out[(m0 + w*16 + quad*4 + r)*3 + col] = pv;
    }
  }
}

// ---------- launch ----------
extern "C" void kernel_launch(void* const* d_in, const int* in_sizes, int n_in,
                              void* d_out, int out_size, void* d_ws, size_t ws_size,
                              hipStream_t stream)
{
  const int*   x     = (const int*)  d_in[0];
  const int*   paths = (const int*)  d_in[1];
  const float* emb   = (const float*)d_in[2];
  const float* Wih_f = (const float*)d_in[3];
  const float* Whh_f = (const float*)d_in[4];
  const float* bih_f = (const float*)d_in[5];
  const float* bhh_f = (const float*)d_in[6];
  const float* Wih_b = (const float*)d_in[7];
  const float* Whh_b = (const float*)d_in[8];
  const float* bih_b = (const float*)d_in[9];
  const float* bhh_b = (const float*)d_in[10];
  const float* W1    = (const float*)d_in[11];
  const float* b1    = (const float*)d_in[12];
  const float* W2    = (const float*)d_in[13];
  const float* b2    = (const float*)d_in[14];
  float* out = (float*)d_out;

  char* ws = (char*)d_ws;
  u16*   xe    = (u16*)  (ws + 0);          //  8,388,608 B
  u16*   wc    = (u16*)  (ws + 8388608);    //    212,992 B
  float* biasC = (float*)(ws + 8601600);    //      3,200 B
  float* whhR  = (float*)(ws + 8604800);    //    320,000 B
  u16*   w1b   = (u16*)  (ws + 8924800);    //    430,080 B
  u16*   inp   = (u16*)  (ws + 9354880);    // 52,428,800 B
  u16*   hbt   = (u16*)  (ws + 61783680);   // 14,680,064 B  (total 76,463,744)

  const int prep_total = 32768*128 + 832*128 + 800 + 80000 + 672*320 + 32768*24;
  prep_kernel<<<(prep_total + 255)/256, 256, 0, stream>>>(
      x, emb, Wih_f, Whh_f, bih_f, bhh_f, Wih_b, Whh_b, bih_b, bhh_b, W1,
      xe, wc, biasC, whhR, w1b, hbt);
  gemm1_kernel<<<dim3(512, 13), 256, 0, stream>>>(xe, wc, biasC, inp);
  lstm_kernel<<<512, 448, 0, stream>>>(inp, whhR, hbt);
  mlp_kernel<<<510, 512, 0, stream>>>(hbt, w1b, paths, b1, W2, b2, out);
}

// Round 7
// 385.230 us; speedup vs baseline: 1.3503x; 1.0853x over previous
//
#include <hip/hip_runtime.h>

typedef unsigned short u16;
typedef short short8 __attribute__((ext_vector_type(8)));
typedef float f32x4 __attribute__((ext_vector_type(4)));

// ---------- helpers ----------
__device__ __forceinline__ u16 f2b(float x){
  union{float f; unsigned u;} v; v.f = x;
  unsigned r = (v.u + 0x7FFFu + ((v.u >> 16) & 1u)) >> 16;
  return (u16)r;
}
__device__ __forceinline__ float b2f(u16 h){
  union{unsigned u; float f;} v; v.u = ((unsigned)h) << 16; return v.f;
}
__device__ __forceinline__ float sigm(float x){ return 1.0f/(1.0f + __expf(-x)); }
__device__ __forceinline__ float tanh_f(float x){ return 1.0f - 2.0f/(1.0f + __expf(2.0f*x)); }

// ---------- prep: xe gather->bf16, Wcomb, bias, Whh row-contiguous quad repack, W1 repack, hbt pad ----------
__global__ void prep_kernel(const int* __restrict__ x, const float* __restrict__ emb,
   const float* __restrict__ Wih_f, const float* __restrict__ Whh_f,
   const float* __restrict__ bih_f, const float* __restrict__ bhh_f,
   const float* __restrict__ Wih_b, const float* __restrict__ Whh_b,
   const float* __restrict__ bih_b, const float* __restrict__ bhh_b,
   const float* __restrict__ W1,
   u16* __restrict__ xe, u16* __restrict__ wc, float* __restrict__ biasC,
   float* __restrict__ whhR, u16* __restrict__ w1b, u16* __restrict__ hbt)
{
  int id = blockIdx.x*256 + threadIdx.x;
  const int N0 = 32768*128;   // xe  [p][k]
  const int N1 = 832*128;     // wc  [n][k]
  const int N2 = 800;         // biasC
  const int N3 = 80000;       // whhR [d][p][k]  p = u*4+g, row g*100+u, k contiguous
  const int N4 = 672*320;     // w1b  (id = k*320+n)
  const int N5 = 32768*24;    // hbt pad cols 200..223
  if (id < N0){
    int p = id >> 7, k = id & 127;
    float v = 0.f;
    if (k < 100) v = emb[x[p]*100 + k];
    xe[id] = f2b(v);
    return;
  }
  id -= N0;
  if (id < N1){
    int n = id >> 7, k = id & 127;
    float v = 0.f;
    if (k < 100){
      if (n < 400) v = Wih_f[n*100+k];
      else if (n < 800) v = Wih_b[(n-400)*100+k];
    }
    wc[id] = f2b(v);
    return;
  }
  id -= N1;
  if (id < N2){
    biasC[id] = (id < 400) ? (bih_f[id]+bhh_f[id]) : (bih_b[id-400]+bhh_b[id-400]);
    return;
  }
  id -= N2;
  if (id < N3){
    int d = id / 40000; int rem = id - d*40000; int p = rem / 100; int k = rem - p*100;
    int uu = p >> 2, gg = p & 3;
    const float* W = d ? Whh_b : Whh_f;
    whhR[id] = W[(gg*100 + uu)*100 + k];
    return;
  }
  id -= N3;
  if (id < N4){
    int k = id / 320; int n = id - k*320;
    int seg = k / 224; int wwk = k - seg*224;
    float v = 0.f;
    if (n < 300 && wwk < 200) v = W1[(seg*200 + wwk)*300 + n];
    w1b[n*672 + k] = f2b(v);
    return;
  }
  id -= N4;
  if (id < N5){
    int p = id / 24; int k = id - p*24;
    hbt[p*224 + 200 + k] = 0;
  }
}

// ---------- GEMM1: inp[d][b][t][u*4+g] = xe @ Wcomb^T + bias, bf16 MFMA ----------
__global__ __launch_bounds__(256) void gemm1_kernel(const u16* __restrict__ xe,
    const u16* __restrict__ wc, const float* __restrict__ biasC, u16* __restrict__ inp)
{
  __shared__ __align__(16) u16 As[64*136];
  __shared__ __align__(16) u16 Bs[64*136];
  const int m0 = blockIdx.x*64, n0 = blockIdx.y*64;
  const int tid = threadIdx.x;
  #pragma unroll
  for (int i=0;i<4;i++){
    int f = i*256 + tid;
    int row = f >> 4, c8 = f & 15;
    *(uint4*)&As[row*136 + c8*8] = *(const uint4*)&xe[(m0+row)*128 + c8*8];
    *(uint4*)&Bs[row*136 + c8*8] = *(const uint4*)&wc[(n0+row)*128 + c8*8];
  }
  __syncthreads();
  const int w = tid >> 6, lane = tid & 63, col = lane & 15, quad = lane >> 4;
  f32x4 acc[4];
  #pragma unroll
  for (int nt=0;nt<4;nt++) acc[nt] = (f32x4){0.f,0.f,0.f,0.f};
  #pragma unroll
  for (int kc=0;kc<4;kc++){
    short8 af = *(const short8*)&As[(w*16+col)*136 + kc*32 + quad*8];
    #pragma unroll
    for (int nt=0;nt<4;nt++){
      short8 bfrag = *(const short8*)&Bs[(nt*16+col)*136 + kc*32 + quad*8];
      acc[nt] = __builtin_amdgcn_mfma_f32_16x16x32_bf16(af, bfrag, acc[nt], 0, 0, 0);
    }
  }
  #pragma unroll
  for (int nt=0;nt<4;nt++){
    int n = n0 + nt*16 + col;
    if (n < 800){
      float bs = biasC[n];
      int dir = (n >= 400) ? 1 : 0;
      int j = n - dir*400;
      int gg = j / 100, uu = j - gg*100;
      int pj = uu*4 + gg;
      #pragma unroll
      for (int r=0;r<4;r++){
        int m = m0 + w*16 + quad*4 + r;
        inp[(dir*32768 + m)*400 + pj] = f2b(acc[nt][r] + bs);
      }
    }
  }
}

// ---------- LSTM recurrence: full-asm inner loop, 124-reg footprint => 2 blocks/CU ----------
// 512 chains, 1 block each, 448 threads; tid -> (u = tid>>2, gate g = tid&3).
// Register map (all clobbered, v0..v123 = 124 regs so total stays <=128 and
// TWO 7-wave blocks co-reside per CU -- round 6's 140-reg clobber allowed only
// one, 20% occupancy, 73% stall):
//   v0-v7   two ds_read_b128 slots (2-deep pipeline, lgkmcnt(1) waits)
//   v8-v11  dot-product accumulators (k mod 4 partition, same order as prior rounds)
//   v12/v13 h read/write LDS addrs (XOR 0x200 per step)  v14 hbt addr  v15 inp addr
//   v16 c-state   v17 prefetched inp   v18-v23 temps
//   v24-v123 the 100 fp32 Whh weights
// Zero VGPR inputs: tid rebuilt via v_mbcnt + wave-id SGPR; bases via SGPRs.
#define G4(W0,W1,W2,W3,S0,S1,S2,S3,OFF) \
  "s_waitcnt lgkmcnt(1)\n\t" \
  "v_fmac_f32 v8,  v" #W0 ", v" #S0 "\n\t" \
  "v_fmac_f32 v9,  v" #W1 ", v" #S1 "\n\t" \
  "v_fmac_f32 v10, v" #W2 ", v" #S2 "\n\t" \
  "v_fmac_f32 v11, v" #W3 ", v" #S3 "\n\t" \
  "ds_read_b128 v[" #S0 ":" #S3 "], v12 offset:" #OFF "\n\t"
#define G4T(W0,W1,W2,W3,S0,S1,S2,S3,CNT) \
  "s_waitcnt lgkmcnt(" #CNT ")\n\t" \
  "v_fmac_f32 v8,  v" #W0 ", v" #S0 "\n\t" \
  "v_fmac_f32 v9,  v" #W1 ", v" #S1 "\n\t" \
  "v_fmac_f32 v10, v" #W2 ", v" #S2 "\n\t" \
  "v_fmac_f32 v11, v" #W3 ", v" #S3 "\n\t"

__global__ __launch_bounds__(448) void lstm_kernel(const u16* __restrict__ inp,
    const float* __restrict__ whhR, u16* __restrict__ hbt)
{
  __shared__ __align__(16) float hs2[2][128];
  const int cid = blockIdx.x;
  const int b = cid & 255, dir = cid >> 8;
  const int tid = threadIdx.x;
  for (int i = tid; i < 256; i += 448) ((float*)hs2)[i] = 0.f;
  __syncthreads();
  if (tid < 400){
    unsigned long long fe  = __ballot(1);
    unsigned long long g0e = __ballot((tid & 3) == 0);
    unsigned long long g1e = __ballot((tid & 3) == 1);
    unsigned long long g1m = __ballot((tid & 1) != 0);
    unsigned long long g2m = __ballot((tid & 2) != 0);
    const int sw  = tid >> 6;                       // wave id (uniform per wave)
    const int t0  = dir ? 127 : 0;
    const int dIb = dir ? -800 : 800;               // inp byte stride per step
    const int dHb = dir ? -448 : 448;               // hbt byte stride per step
    const int s4h = 400;                            // weight bytes per thread row
    const int swb = dir*160000;                     // whhR dir base (bytes)
    const unsigned sio = (unsigned)((dir*32768 + b*128 + t0)*400) * 2u;
    const unsigned sho = (unsigned)((b*128 + t0)*224 + dir*100) * 2u;
    const unsigned sra = (unsigned)(size_t)&hs2[0][0];
    const unsigned sha = sra + 512u;
    asm volatile(
      // ---- rebuild tid, compute all per-thread addresses in clobbered regs ----
      "v_mbcnt_lo_u32_b32 v0, -1, 0\n\t"
      "v_mbcnt_hi_u32_b32 v0, -1, v0\n\t"           // lane
      "v_lshl_add_u32 v0, %[sw], 6, v0\n\t"         // tid
      "v_mul_lo_u32 v1, %[s4h], v0\n\t"
      "v_add_u32 v1, %[swb], v1\n\t"                // weight base (bytes)
      "v_lshl_add_u32 v15, v0, 1, %[sio]\n\t"       // inp addr
      "v_lshrrev_b32 v2, 2, v0\n\t"                 // u
      "v_lshl_add_u32 v14, v2, 1, %[sho]\n\t"       // hbt addr
      "v_lshl_add_u32 v13, v2, 2, %[sha]\n\t"       // h write addr (buf1)
      "v_mov_b32 v12, %[sra]\n\t"                   // h read addr (buf0)
      "v_mov_b32 v16, 0\n\t"                        // c
      "s_mov_b32 s20, 128\n\t"
      "global_load_ushort v17, v15, %[ib]\n\t"
      "v_add_u32 v15, %[dis], v15\n\t"
      "global_load_dwordx4 v[24:27],   v1, %[wb]\n\t"
      "global_load_dwordx4 v[28:31],   v1, %[wb] offset:16\n\t"
      "global_load_dwordx4 v[32:35],   v1, %[wb] offset:32\n\t"
      "global_load_dwordx4 v[36:39],   v1, %[wb] offset:48\n\t"
      "global_load_dwordx4 v[40:43],   v1, %[wb] offset:64\n\t"
      "global_load_dwordx4 v[44:47],   v1, %[wb] offset:80\n\t"
      "global_load_dwordx4 v[48:51],   v1, %[wb] offset:96\n\t"
      "global_load_dwordx4 v[52:55],   v1, %[wb] offset:112\n\t"
      "global_load_dwordx4 v[56:59],   v1, %[wb] offset:128\n\t"
      "global_load_dwordx4 v[60:63],   v1, %[wb] offset:144\n\t"
      "global_load_dwordx4 v[64:67],   v1, %[wb] offset:160\n\t"
      "global_load_dwordx4 v[68:71],   v1, %[wb] offset:176\n\t"
      "global_load_dwordx4 v[72:75],   v1, %[wb] offset:192\n\t"
      "global_load_dwordx4 v[76:79],   v1, %[wb] offset:208\n\t"
      "global_load_dwordx4 v[80:83],   v1, %[wb] offset:224\n\t"
      "global_load_dwordx4 v[84:87],   v1, %[wb] offset:240\n\t"
      "global_load_dwordx4 v[88:91],   v1, %[wb] offset:256\n\t"
      "global_load_dwordx4 v[92:95],   v1, %[wb] offset:272\n\t"
      "global_load_dwordx4 v[96:99],   v1, %[wb] offset:288\n\t"
      "global_load_dwordx4 v[100:103], v1, %[wb] offset:304\n\t"
      "global_load_dwordx4 v[104:107], v1, %[wb] offset:320\n\t"
      "global_load_dwordx4 v[108:111], v1, %[wb] offset:336\n\t"
      "global_load_dwordx4 v[112:115], v1, %[wb] offset:352\n\t"
      "global_load_dwordx4 v[116:119], v1, %[wb] offset:368\n\t"
      "global_load_dwordx4 v[120:123], v1, %[wb] offset:384\n\t"
      "LSTM_T%=:\n\t"
      // pre0 from prefetched inp; reissue next step's load
      "s_waitcnt vmcnt(0)\n\t"
      "v_lshlrev_b32 v18, 16, v17\n\t"              // pre0 (bf16 -> f32)
      "global_load_ushort v17, v15, %[ib]\n\t"
      "v_add_u32 v15, %[dis], v15\n\t"
      // h dot: 2-slot pipelined broadcast reads + 100 fmac
      "ds_read_b128 v[0:3], v12\n\t"
      "ds_read_b128 v[4:7], v12 offset:16\n\t"
      "v_mov_b32 v8, 0\n\t"
      "v_mov_b32 v9, 0\n\t"
      "v_mov_b32 v10, 0\n\t"
      "v_mov_b32 v11, 0\n\t"
      G4(24,25,26,27,      0,1,2,3,    32)
      G4(28,29,30,31,      4,5,6,7,    48)
      G4(32,33,34,35,      0,1,2,3,    64)
      G4(36,37,38,39,      4,5,6,7,    80)
      G4(40,41,42,43,      0,1,2,3,    96)
      G4(44,45,46,47,      4,5,6,7,    112)
      G4(48,49,50,51,      0,1,2,3,    128)
      G4(52,53,54,55,      4,5,6,7,    144)
      G4(56,57,58,59,      0,1,2,3,    160)
      G4(60,61,62,63,      4,5,6,7,    176)
      G4(64,65,66,67,      0,1,2,3,    192)
      G4(68,69,70,71,      4,5,6,7,    208)
      G4(72,73,74,75,      0,1,2,3,    224)
      G4(76,77,78,79,      4,5,6,7,    240)
      G4(80,81,82,83,      0,1,2,3,    256)
      G4(84,85,86,87,      4,5,6,7,    272)
      G4(88,89,90,91,      0,1,2,3,    288)
      G4(92,93,94,95,      4,5,6,7,    304)
      G4(96,97,98,99,      0,1,2,3,    320)
      G4(100,101,102,103,  4,5,6,7,    336)
      G4(104,105,106,107,  0,1,2,3,    352)
      G4(108,109,110,111,  4,5,6,7,    368)
      G4(112,113,114,115,  0,1,2,3,    384)
      G4T(116,117,118,119, 4,5,6,7,    1)
      G4T(120,121,122,123, 0,1,2,3,    0)
      "v_add_f32 v8, v8, v9\n\t"
      "v_add_f32 v10, v10, v11\n\t"
      "v_add_f32 v8, v8, v10\n\t"
      "v_add_f32 v18, v8, v18\n\t"                  // pre
      // quad gather: s1 = xor1, t2 = xor2, t3 = xor2(s1)
      "ds_swizzle_b32 v19, v18 offset:0x041f\n\t"
      "ds_swizzle_b32 v20, v18 offset:0x081f\n\t"
      "s_waitcnt lgkmcnt(0)\n\t"
      "ds_swizzle_b32 v21, v19 offset:0x081f\n\t"
      "s_waitcnt lgkmcnt(0)\n\t"
      "v_cndmask_b32 v22, v18, v19, %[g1m]\n\t"     // A = g1? s1 : pre
      "v_cndmask_b32 v19, v19, v18, %[g1m]\n\t"     // C = g1? pre : s1
      "v_cndmask_b32 v23, v20, v21, %[g1m]\n\t"     // B = g1? t3 : t2
      "v_cndmask_b32 v20, v21, v20, %[g1m]\n\t"     // D = g1? t2 : t3
      "v_cndmask_b32 v18, v22, v23, %[g2m]\n\t"     // iv
      "v_cndmask_b32 v21, v23, v22, %[g2m]\n\t"     // gv
      "v_cndmask_b32 v22, v19, v20, %[g2m]\n\t"     // fv
      "v_cndmask_b32 v23, v20, v19, %[g2m]\n\t"     // ov
      // activations (identical constants/order to round 6 -- passed)
      "v_mul_f32 v19, 0xbfb8aa3b, v22\n\t"
      "v_mul_f32 v20, 0xbfb8aa3b, v18\n\t"
      "v_mul_f32 v22, 0x4038aa3b, v21\n\t"
      "v_exp_f32 v19, v19\n\t"
      "v_exp_f32 v20, v20\n\t"
      "v_exp_f32 v22, v22\n\t"
      "v_add_f32 v19, 1.0, v19\n\t"
      "v_add_f32 v20, 1.0, v20\n\t"
      "v_add_f32 v22, 1.0, v22\n\t"
      "v_rcp_f32 v19, v19\n\t"                      // sf
      "v_rcp_f32 v20, v20\n\t"                      // si
      "v_rcp_f32 v22, v22\n\t"
      "v_mov_b32 v18, 1.0\n\t"
      "v_fmac_f32 v18, -2.0, v22\n\t"               // tg
      "v_mul_f32 v20, v20, v18\n\t"                 // si*tg
      "v_fmac_f32 v20, v19, v16\n\t"                // + sf*c
      "v_mov_b32 v16, v20\n\t"                      // c
      "v_mul_f32 v19, 0x4038aa3b, v16\n\t"
      "v_mul_f32 v21, 0xbfb8aa3b, v23\n\t"
      "v_exp_f32 v19, v19\n\t"
      "v_exp_f32 v21, v21\n\t"
      "v_add_f32 v19, 1.0, v19\n\t"
      "v_add_f32 v21, 1.0, v21\n\t"
      "v_rcp_f32 v19, v19\n\t"
      "v_rcp_f32 v21, v21\n\t"                      // so
      "v_mov_b32 v18, 1.0\n\t"
      "v_fmac_f32 v18, -2.0, v19\n\t"               // tc
      "v_mul_f32 v20, v21, v18\n\t"                 // h
      "v_cvt_pk_bf16_f32 v22, v20, v20\n\t"
      // exec-masked stores: h -> LDS (g==0), h_bf16 -> hbt (g==1)
      "s_mov_b64 exec, %[g0e]\n\t"
      "ds_write_b32 v13, v20\n\t"
      "s_mov_b64 exec, %[g1e]\n\t"
      "global_store_short v14, v22, %[hb]\n\t"
      "s_mov_b64 exec, %[fe]\n\t"
      "v_add_u32 v14, %[dhs], v14\n\t"
      "v_xor_b32 v12, 0x200, v12\n\t"
      "v_xor_b32 v13, 0x200, v13\n\t"
      "s_waitcnt lgkmcnt(0)\n\t"
      "s_barrier\n\t"
      "s_sub_u32 s20, s20, 1\n\t"
      "s_cmp_lg_u32 s20, 0\n\t"
      "s_cbranch_scc1 LSTM_T%=\n\t"
      :
      : [sw]"s"(sw), [s4h]"s"(s4h), [swb]"s"(swb),
        [sio]"s"(sio), [sho]"s"(sho), [sra]"s"(sra), [sha]"s"(sha),
        [wb]"s"(whhR), [ib]"s"(inp), [hb]"s"(hbt),
        [dis]"s"(dIb), [dhs]"s"(dHb),
        [fe]"s"(fe), [g0e]"s"(g0e), [g1e]"s"(g1e), [g1m]"s"(g1m), [g2m]"s"(g2m)
      : "memory","scc","s20",
        "v0","v1","v2","v3","v4","v5","v6","v7","v8","v9",
        "v10","v11","v12","v13","v14","v15","v16","v17","v18","v19",
        "v20","v21","v22","v23","v24","v25","v26","v27","v28","v29",
        "v30","v31","v32","v33","v34","v35","v36","v37","v38","v39",
        "v40","v41","v42","v43","v44","v45","v46","v47","v48","v49",
        "v50","v51","v52","v53","v54","v55","v56","v57","v58","v59",
        "v60","v61","v62","v63","v64","v65","v66","v67","v68","v69",
        "v70","v71","v72","v73","v74","v75","v76","v77","v78","v79",
        "v80","v81","v82","v83","v84","v85","v86","v87","v88","v89",
        "v90","v91","v92","v93","v94","v95","v96","v97","v98","v99",
        "v100","v101","v102","v103","v104","v105","v106","v107","v108","v109",
        "v110","v111","v112","v113","v114","v115","v116","v117","v118","v119",
        "v120","v121","v122","v123"
    );
  }
}

// ---------- MLP: gathered bf16 MFMA GEMM + tanh + W2 + softmax fused ----------
__global__ __launch_bounds__(512) void mlp_kernel(const u16* __restrict__ hbt,
    const u16* __restrict__ w1b, const int* __restrict__ paths,
    const float* __restrict__ b1, const float* __restrict__ W2,
    const float* __restrict__ b2, float* __restrict__ out)
{
  __shared__ __align__(16) u16 As[128*40];
  __shared__ __align__(16) u16 Bs[320*40];
  const int m0 = blockIdx.x*128;
  const int tid = threadIdx.x;
  const int arow = tid >> 2, ac8 = tid & 3;
  const int am = m0 + arow;
  const int ab = am / 255;
  const int w = tid >> 6, lane = tid & 63, col = lane & 15, quad = lane >> 4;
  f32x4 acc[20];
  #pragma unroll
  for (int nt=0;nt<20;nt++) acc[nt] = (f32x4){0.f,0.f,0.f,0.f};
  for (int kc=0;kc<21;kc++){
    __syncthreads();
    for (int f = tid; f < 1280; f += 512){
      int br = f >> 2, bc = f & 3;
      *(uint4*)&Bs[br*40 + bc*8] = *(const uint4*)&w1b[br*672 + kc*32 + bc*8];
    }
    int seg = (kc >= 14) ? 2 : (kc >= 7 ? 1 : 0);
    int ko = kc - seg*7;
    int it = paths[am*3 + seg];
    uint4 v = make_uint4(0u,0u,0u,0u);
    if (it >= 0){
      int t = it > 127 ? 127 : it;
      v = *(const uint4*)&hbt[(ab*128 + t)*224 + ko*32 + ac8*8];
    }
    *(uint4*)&As[arow*40 + ac8*8] = v;
    __syncthreads();
    short8 af = *(const short8*)&As[(w*16+col)*40 + quad*8];
    #pragma unroll
    for (int nt=0;nt<20;nt++){
      short8 bfrag = *(const short8*)&Bs[(nt*16+col)*40 + quad*8];
      acc[nt] = __builtin_amdgcn_mfma_f32_16x16x32_bf16(af, bfrag, acc[nt], 0, 0, 0);
    }
  }
  float pz[4][3];
  #pragma unroll
  for (int r=0;r<4;r++){ pz[r][0]=0.f; pz[r][1]=0.f; pz[r][2]=0.f; }
  #pragma unroll
  for (int nt=0;nt<20;nt++){
    int n = nt*16 + col;
    if (n < 300){
      float bb = b1[n];
      float w20 = W2[n*3+0], w21 = W2[n*3+1], w22 = W2[n*3+2];
      #pragma unroll
      for (int r=0;r<4;r++){
        float hdn = tanh_f(acc[nt][r] + bb);
        pz[r][0] = fmaf(hdn, w20, pz[r][0]);
        pz[r][1] = fmaf(hdn, w21, pz[r][1]);
        pz[r][2] = fmaf(hdn, w22, pz[r][2]);
      }
    }
  }
  #pragma unroll
  for (int off=1; off<16; off<<=1){
    #pragma unroll
    for (int r=0;r<4;r++){
      pz[r][0] += __shfl_xor(pz[r][0], off, 64);
      pz[r][1] += __shfl_xor(pz[r][1], off, 64);
      pz[r][2] += __shfl_xor(pz[r][2], off, 64);
    }
  }
  float c0 = b2[0], c1 = b2[1], c2 = b2[2];
  #pragma unroll
  for (int r=0;r<4;r++){
    float z0 = pz[r][0]+c0, z1 = pz[r][1]+c1, z2 = pz[r][2]+c2;
    float mx = fmaxf(z0, fmaxf(z1, z2));
    float e0 = __expf(z0-mx), e1 = __expf(z1-mx), e2 = __expf(z2-mx);
    float inv = 1.0f/(e0+e1+e2);
    if (col < 3){
      float pv = (col==0 ? e0 : (col==1 ? e1 : e2)) * inv;
      out[(m0 + w*16 + quad*4 + r)*3 + col] = pv;
    }
  }
}

// ---------- launch ----------
extern "C" void kernel_launch(void* const* d_in, const int* in_sizes, int n_in,
                              void* d_out, int out_size, void* d_ws, size_t ws_size,
                              hipStream_t stream)
{
  const int*   x     = (const int*)  d_in[0];
  const int*   paths = (const int*)  d_in[1];
  const float* emb   = (const float*)d_in[2];
  const float* Wih_f = (const float*)d_in[3];
  const float* Whh_f = (const float*)d_in[4];
  const float* bih_f = (const float*)d_in[5];
  const float* bhh_f = (const float*)d_in[6];
  const float* Wih_b = (const float*)d_in[7];
  const float* Whh_b = (const float*)d_in[8];
  const float* bih_b = (const float*)d_in[9];
  const float* bhh_b = (const float*)d_in[10];
  const float* W1    = (const float*)d_in[11];
  const float* b1    = (const float*)d_in[12];
  const float* W2    = (const float*)d_in[13];
  const float* b2    = (const float*)d_in[14];
  float* out = (float*)d_out;

  char* ws = (char*)d_ws;
  u16*   xe    = (u16*)  (ws + 0);          //  8,388,608 B
  u16*   wc    = (u16*)  (ws + 8388608);    //    212,992 B
  float* biasC = (float*)(ws + 8601600);    //      3,200 B
  float* whhR  = (float*)(ws + 8604800);    //    320,000 B
  u16*   w1b   = (u16*)  (ws + 8924800);    //    430,080 B
  u16*   inp   = (u16*)  (ws + 9354880);    // 52,428,800 B
  u16*   hbt   = (u16*)  (ws + 61783680);   // 14,680,064 B  (total 76,463,744)

  const int prep_total = 32768*128 + 832*128 + 800 + 80000 + 672*320 + 32768*24;
  prep_kernel<<<(prep_total + 255)/256, 256, 0, stream>>>(
      x, emb, Wih_f, Whh_f, bih_f, bhh_f, Wih_b, Whh_b, bih_b, bhh_b, W1,
      xe, wc, biasC, whhR, w1b, hbt);
  gemm1_kernel<<<dim3(512, 13), 256, 0, stream>>>(xe, wc, biasC, inp);
  lstm_kernel<<<512, 448, 0, stream>>>(inp, whhR, hbt);
  mlp_kernel<<<510, 512, 0, stream>>>(hbt, w1b, paths, b1, W2, b2, out);
}

// Round 8
// 368.582 us; speedup vs baseline: 1.4113x; 1.0452x over previous
//
#include <hip/hip_runtime.h>

typedef unsigned short u16;
typedef short short8 __attribute__((ext_vector_type(8)));
typedef float f32x4 __attribute__((ext_vector_type(4)));

// ---------- helpers ----------
__device__ __forceinline__ u16 f2b(float x){
  union{float f; unsigned u;} v; v.f = x;
  unsigned r = (v.u + 0x7FFFu + ((v.u >> 16) & 1u)) >> 16;
  return (u16)r;
}
__device__ __forceinline__ u16 f2h(float x){
  union{_Float16 h; u16 u;} c; c.h = (_Float16)x; return c.u;
}
__device__ __forceinline__ float b2f(u16 h){
  union{unsigned u; float f;} v; v.u = ((unsigned)h) << 16; return v.f;
}
__device__ __forceinline__ float sigm(float x){ return 1.0f/(1.0f + __expf(-x)); }
__device__ __forceinline__ float tanh_f(float x){ return 1.0f - 2.0f/(1.0f + __expf(2.0f*x)); }

// ---------- prep: xe gather->bf16, Wcomb, bias, Whh f16 quad repack, W1 repack, hbt pad ----------
__global__ void prep_kernel(const int* __restrict__ x, const float* __restrict__ emb,
   const float* __restrict__ Wih_f, const float* __restrict__ Whh_f,
   const float* __restrict__ bih_f, const float* __restrict__ bhh_f,
   const float* __restrict__ Wih_b, const float* __restrict__ Whh_b,
   const float* __restrict__ bih_b, const float* __restrict__ bhh_b,
   const float* __restrict__ W1,
   u16* __restrict__ xe, u16* __restrict__ wc, float* __restrict__ biasC,
   u16* __restrict__ whhH, u16* __restrict__ w1b, u16* __restrict__ hbt)
{
  int id = blockIdx.x*256 + threadIdx.x;
  const int N0 = 32768*128;   // xe  [p][k]
  const int N1 = 832*128;     // wc  [n][k]
  const int N2 = 800;         // biasC
  const int N3 = 83200;       // whhH [d][p(400)][k(104 f16)]  p = u*4+g, row g*100+u
  const int N4 = 672*320;     // w1b  (id = k*320+n)
  const int N5 = 32768*24;    // hbt pad cols 200..223
  if (id < N0){
    int p = id >> 7, k = id & 127;
    float v = 0.f;
    if (k < 100) v = emb[x[p]*100 + k];
    xe[id] = f2b(v);
    return;
  }
  id -= N0;
  if (id < N1){
    int n = id >> 7, k = id & 127;
    float v = 0.f;
    if (k < 100){
      if (n < 400) v = Wih_f[n*100+k];
      else if (n < 800) v = Wih_b[(n-400)*100+k];
    }
    wc[id] = f2b(v);
    return;
  }
  id -= N1;
  if (id < N2){
    biasC[id] = (id < 400) ? (bih_f[id]+bhh_f[id]) : (bih_b[id-400]+bhh_b[id-400]);
    return;
  }
  id -= N2;
  if (id < N3){
    int d = id / 41600; int rem = id - d*41600; int p = rem / 104; int k = rem - p*104;
    int uu = p >> 2, gg = p & 3;
    float v = 0.f;
    if (k < 100){
      const float* W = d ? Whh_b : Whh_f;
      v = W[(gg*100 + uu)*100 + k];
    }
    whhH[id] = f2h(v);
    return;
  }
  id -= N3;
  if (id < N4){
    int k = id / 320; int n = id - k*320;
    int seg = k / 224; int wwk = k - seg*224;
    float v = 0.f;
    if (n < 300 && wwk < 200) v = W1[(seg*200 + wwk)*300 + n];
    w1b[n*672 + k] = f2b(v);
    return;
  }
  id -= N4;
  if (id < N5){
    int p = id / 24; int k = id - p*24;
    hbt[p*224 + 200 + k] = 0;
  }
}

// ---------- GEMM1: inp[d][b][t][u*4+g] = xe @ Wcomb^T + bias, bf16 MFMA ----------
__global__ __launch_bounds__(256) void gemm1_kernel(const u16* __restrict__ xe,
    const u16* __restrict__ wc, const float* __restrict__ biasC, u16* __restrict__ inp)
{
  __shared__ __align__(16) u16 As[64*136];
  __shared__ __align__(16) u16 Bs[64*136];
  const int m0 = blockIdx.x*64, n0 = blockIdx.y*64;
  const int tid = threadIdx.x;
  #pragma unroll
  for (int i=0;i<4;i++){
    int f = i*256 + tid;
    int row = f >> 4, c8 = f & 15;
    *(uint4*)&As[row*136 + c8*8] = *(const uint4*)&xe[(m0+row)*128 + c8*8];
    *(uint4*)&Bs[row*136 + c8*8] = *(const uint4*)&wc[(n0+row)*128 + c8*8];
  }
  __syncthreads();
  const int w = tid >> 6, lane = tid & 63, col = lane & 15, quad = lane >> 4;
  f32x4 acc[4];
  #pragma unroll
  for (int nt=0;nt<4;nt++) acc[nt] = (f32x4){0.f,0.f,0.f,0.f};
  #pragma unroll
  for (int kc=0;kc<4;kc++){
    short8 af = *(const short8*)&As[(w*16+col)*136 + kc*32 + quad*8];
    #pragma unroll
    for (int nt=0;nt<4;nt++){
      short8 bfrag = *(const short8*)&Bs[(nt*16+col)*136 + kc*32 + quad*8];
      acc[nt] = __builtin_amdgcn_mfma_f32_16x16x32_bf16(af, bfrag, acc[nt], 0, 0, 0);
    }
  }
  #pragma unroll
  for (int nt=0;nt<4;nt++){
    int n = n0 + nt*16 + col;
    if (n < 800){
      float bs = biasC[n];
      int dir = (n >= 400) ? 1 : 0;
      int j = n - dir*400;
      int gg = j / 100, uu = j - gg*100;
      int pj = uu*4 + gg;
      #pragma unroll
      for (int r=0;r<4;r++){
        int m = m0 + w*16 + quad*4 + r;
        inp[(dir*32768 + m)*400 + pj] = f2b(acc[nt][r] + bs);
      }
    }
  }
}

// ---------- LSTM recurrence: full-asm, f16-packed h + weights, v_dot2_f32_f16 ----------
// LDS-throughput was the floor (r7: 25 b128 x 12.5 waves ~ 3100 cyc/step). f16
// packing halves it: h in LDS as 104 f16 (13 b128 reads), Whh as 52 f16-pair
// regs, 52 dot2 = 104 MACs. 4-slot ds pipeline. Footprint v0..v83 (84 regs),
// 2 blocks/CU. Gather/activation/store tail byte-identical to round 7 (passed).
//   v0-7,v76-83 four ds slots | v8-11 acc | v12 h-rd v13 h-wr v14 hbt v15 inp
//   v16 c  v17 inp-prefetch  v18-23 temps | v24-75 52 weight dwords (104 f16)
#define D4(W0,W1,W2,W3,S0,S1,S2,S3,OFF) \
  "s_waitcnt lgkmcnt(3)\n\t" \
  "v_dot2_f32_f16 v8,  v" #W0 ", v" #S0 ", v8\n\t" \
  "v_dot2_f32_f16 v9,  v" #W1 ", v" #S1 ", v9\n\t" \
  "v_dot2_f32_f16 v10, v" #W2 ", v" #S2 ", v10\n\t" \
  "v_dot2_f32_f16 v11, v" #W3 ", v" #S3 ", v11\n\t" \
  "ds_read_b128 v[" #S0 ":" #S3 "], v12 offset:" #OFF "\n\t"
#define D4T(W0,W1,W2,W3,S0,S1,S2,S3,CNT) \
  "s_waitcnt lgkmcnt(" #CNT ")\n\t" \
  "v_dot2_f32_f16 v8,  v" #W0 ", v" #S0 ", v8\n\t" \
  "v_dot2_f32_f16 v9,  v" #W1 ", v" #S1 ", v9\n\t" \
  "v_dot2_f32_f16 v10, v" #W2 ", v" #S2 ", v10\n\t" \
  "v_dot2_f32_f16 v11, v" #W3 ", v" #S3 ", v11\n\t"

__global__ __launch_bounds__(448) void lstm_kernel(const u16* __restrict__ inp,
    const u16* __restrict__ whhH, u16* __restrict__ hbt)
{
  __shared__ __align__(512) u16 hs2[256];   // [2][128] f16: buf stride 256B, XOR 0x100
  const int cid = blockIdx.x;
  const int b = cid & 255, dir = cid >> 8;
  const int tid = threadIdx.x;
  for (int i = tid; i < 128; i += 448) ((float*)hs2)[i] = 0.f;
  __syncthreads();
  if (tid < 400){
    unsigned long long fe  = __ballot(1);
    unsigned long long g0e = __ballot((tid & 3) == 0);
    unsigned long long g1e = __ballot((tid & 3) == 1);
    unsigned long long g1m = __ballot((tid & 1) != 0);
    unsigned long long g2m = __ballot((tid & 2) != 0);
    const int sw  = tid >> 6;                       // wave id (uniform per wave)
    const int t0  = dir ? 127 : 0;
    const int dIb = dir ? -800 : 800;               // inp byte stride per step
    const int dHb = dir ? -448 : 448;               // hbt byte stride per step
    const int swb = dir*83200;                      // whhH dir base (bytes)
    const unsigned sio = (unsigned)((dir*32768 + b*128 + t0)*400) * 2u;
    const unsigned sho = (unsigned)((b*128 + t0)*224 + dir*100) * 2u;
    const unsigned sra = (unsigned)(size_t)&hs2[0];
    const unsigned sha = sra + 256u;
    asm volatile(
      // ---- rebuild tid, compute per-thread addresses in clobbered regs ----
      "v_mbcnt_lo_u32_b32 v0, -1, 0\n\t"
      "v_mbcnt_hi_u32_b32 v0, -1, v0\n\t"           // lane
      "v_lshl_add_u32 v0, %[sw], 6, v0\n\t"         // tid
      "v_mul_u32_u24 v1, 208, v0\n\t"               // tid*208 (weight row bytes)
      "v_add_u32 v1, %[swb], v1\n\t"
      "v_lshl_add_u32 v15, v0, 1, %[sio]\n\t"       // inp addr
      "v_lshrrev_b32 v2, 2, v0\n\t"                 // u
      "v_lshl_add_u32 v14, v2, 1, %[sho]\n\t"       // hbt addr
      "v_lshl_add_u32 v13, v2, 1, %[sha]\n\t"       // h write addr (buf1, f16)
      "v_mov_b32 v12, %[sra]\n\t"                   // h read addr (buf0)
      "v_mov_b32 v16, 0\n\t"                        // c
      "s_mov_b32 s20, 128\n\t"
      "global_load_ushort v17, v15, %[ib]\n\t"
      "v_add_u32 v15, %[dis], v15\n\t"
      "global_load_dwordx4 v[24:27], v1, %[wb]\n\t"
      "global_load_dwordx4 v[28:31], v1, %[wb] offset:16\n\t"
      "global_load_dwordx4 v[32:35], v1, %[wb] offset:32\n\t"
      "global_load_dwordx4 v[36:39], v1, %[wb] offset:48\n\t"
      "global_load_dwordx4 v[40:43], v1, %[wb] offset:64\n\t"
      "global_load_dwordx4 v[44:47], v1, %[wb] offset:80\n\t"
      "global_load_dwordx4 v[48:51], v1, %[wb] offset:96\n\t"
      "global_load_dwordx4 v[52:55], v1, %[wb] offset:112\n\t"
      "global_load_dwordx4 v[56:59], v1, %[wb] offset:128\n\t"
      "global_load_dwordx4 v[60:63], v1, %[wb] offset:144\n\t"
      "global_load_dwordx4 v[64:67], v1, %[wb] offset:160\n\t"
      "global_load_dwordx4 v[68:71], v1, %[wb] offset:176\n\t"
      "global_load_dwordx4 v[72:75], v1, %[wb] offset:192\n\t"
      "LSTM_T%=:\n\t"
      // pre0 from prefetched inp; reissue next step's load
      "s_waitcnt vmcnt(0)\n\t"
      "v_lshlrev_b32 v18, 16, v17\n\t"              // pre0 (bf16 -> f32)
      "global_load_ushort v17, v15, %[ib]\n\t"
      "v_add_u32 v15, %[dis], v15\n\t"
      // h dot: 4-slot pipelined broadcast reads + 52 dot2 (104 MACs)
      "ds_read_b128 v[0:3], v12\n\t"
      "ds_read_b128 v[4:7], v12 offset:16\n\t"
      "ds_read_b128 v[76:79], v12 offset:32\n\t"
      "ds_read_b128 v[80:83], v12 offset:48\n\t"
      "v_mov_b32 v8, 0\n\t"
      "v_mov_b32 v9, 0\n\t"
      "v_mov_b32 v10, 0\n\t"
      "v_mov_b32 v11, 0\n\t"
      D4(24,25,26,27,  0,1,2,3,     64)
      D4(28,29,30,31,  4,5,6,7,     80)
      D4(32,33,34,35,  76,77,78,79, 96)
      D4(36,37,38,39,  80,81,82,83, 112)
      D4(40,41,42,43,  0,1,2,3,     128)
      D4(44,45,46,47,  4,5,6,7,     144)
      D4(48,49,50,51,  76,77,78,79, 160)
      D4(52,53,54,55,  80,81,82,83, 176)
      D4(56,57,58,59,  0,1,2,3,     192)
      D4T(60,61,62,63, 4,5,6,7,     3)
      D4T(64,65,66,67, 76,77,78,79, 2)
      D4T(68,69,70,71, 80,81,82,83, 1)
      D4T(72,73,74,75, 0,1,2,3,     0)
      "v_add_f32 v8, v8, v9\n\t"
      "v_add_f32 v10, v10, v11\n\t"
      "v_add_f32 v8, v8, v10\n\t"
      "v_add_f32 v18, v8, v18\n\t"                  // pre
      // quad gather: s1 = xor1, t2 = xor2, t3 = xor2(s1)  (identical to r7)
      "ds_swizzle_b32 v19, v18 offset:0x041f\n\t"
      "ds_swizzle_b32 v20, v18 offset:0x081f\n\t"
      "s_waitcnt lgkmcnt(0)\n\t"
      "ds_swizzle_b32 v21, v19 offset:0x081f\n\t"
      "s_waitcnt lgkmcnt(0)\n\t"
      "v_cndmask_b32 v22, v18, v19, %[g1m]\n\t"     // A = g1? s1 : pre
      "v_cndmask_b32 v19, v19, v18, %[g1m]\n\t"     // C = g1? pre : s1
      "v_cndmask_b32 v23, v20, v21, %[g1m]\n\t"     // B = g1? t3 : t2
      "v_cndmask_b32 v20, v21, v20, %[g1m]\n\t"     // D = g1? t2 : t3
      "v_cndmask_b32 v18, v22, v23, %[g2m]\n\t"     // iv
      "v_cndmask_b32 v21, v23, v22, %[g2m]\n\t"     // gv
      "v_cndmask_b32 v22, v19, v20, %[g2m]\n\t"     // fv
      "v_cndmask_b32 v23, v20, v19, %[g2m]\n\t"     // ov
      // activations (identical constants/order to rounds 6/7 -- passed)
      "v_mul_f32 v19, 0xbfb8aa3b, v22\n\t"
      "v_mul_f32 v20, 0xbfb8aa3b, v18\n\t"
      "v_mul_f32 v22, 0x4038aa3b, v21\n\t"
      "v_exp_f32 v19, v19\n\t"
      "v_exp_f32 v20, v20\n\t"
      "v_exp_f32 v22, v22\n\t"
      "v_add_f32 v19, 1.0, v19\n\t"
      "v_add_f32 v20, 1.0, v20\n\t"
      "v_add_f32 v22, 1.0, v22\n\t"
      "v_rcp_f32 v19, v19\n\t"                      // sf
      "v_rcp_f32 v20, v20\n\t"                      // si
      "v_rcp_f32 v22, v22\n\t"
      "v_mov_b32 v18, 1.0\n\t"
      "v_fmac_f32 v18, -2.0, v22\n\t"               // tg
      "v_mul_f32 v20, v20, v18\n\t"                 // si*tg
      "v_fmac_f32 v20, v19, v16\n\t"                // + sf*c
      "v_mov_b32 v16, v20\n\t"                      // c
      "v_mul_f32 v19, 0x4038aa3b, v16\n\t"
      "v_mul_f32 v21, 0xbfb8aa3b, v23\n\t"
      "v_exp_f32 v19, v19\n\t"
      "v_exp_f32 v21, v21\n\t"
      "v_add_f32 v19, 1.0, v19\n\t"
      "v_add_f32 v21, 1.0, v21\n\t"
      "v_rcp_f32 v19, v19\n\t"
      "v_rcp_f32 v21, v21\n\t"                      // so
      "v_mov_b32 v18, 1.0\n\t"
      "v_fmac_f32 v18, -2.0, v19\n\t"               // tc
      "v_mul_f32 v20, v21, v18\n\t"                 // h
      "v_cvt_pk_bf16_f32 v22, v20, v20\n\t"         // bf16 for hbt
      "v_cvt_f16_f32 v19, v20\n\t"                  // f16 for LDS h
      // exec-masked stores: h(f16) -> LDS (g==0), h(bf16) -> hbt (g==1)
      "s_mov_b64 exec, %[g0e]\n\t"
      "ds_write_b16 v13, v19\n\t"
      "s_mov_b64 exec, %[g1e]\n\t"
      "global_store_short v14, v22, %[hb]\n\t"
      "s_mov_b64 exec, %[fe]\n\t"
      "v_add_u32 v14, %[dhs], v14\n\t"
      "v_xor_b32 v12, 0x100, v12\n\t"
      "v_xor_b32 v13, 0x100, v13\n\t"
      "s_waitcnt lgkmcnt(0)\n\t"
      "s_barrier\n\t"
      "s_sub_u32 s20, s20, 1\n\t"
      "s_cmp_lg_u32 s20, 0\n\t"
      "s_cbranch_scc1 LSTM_T%=\n\t"
      :
      : [sw]"s"(sw), [swb]"s"(swb),
        [sio]"s"(sio), [sho]"s"(sho), [sra]"s"(sra), [sha]"s"(sha),
        [wb]"s"(whhH), [ib]"s"(inp), [hb]"s"(hbt),
        [dis]"s"(dIb), [dhs]"s"(dHb),
        [fe]"s"(fe), [g0e]"s"(g0e), [g1e]"s"(g1e), [g1m]"s"(g1m), [g2m]"s"(g2m)
      : "memory","scc","s20",
        "v0","v1","v2","v3","v4","v5","v6","v7","v8","v9",
        "v10","v11","v12","v13","v14","v15","v16","v17","v18","v19",
        "v20","v21","v22","v23","v24","v25","v26","v27","v28","v29",
        "v30","v31","v32","v33","v34","v35","v36","v37","v38","v39",
        "v40","v41","v42","v43","v44","v45","v46","v47","v48","v49",
        "v50","v51","v52","v53","v54","v55","v56","v57","v58","v59",
        "v60","v61","v62","v63","v64","v65","v66","v67","v68","v69",
        "v70","v71","v72","v73","v74","v75","v76","v77","v78","v79",
        "v80","v81","v82","v83"
    );
  }
}

// ---------- MLP: gathered bf16 MFMA GEMM + tanh + W2 + softmax fused ----------
__global__ __launch_bounds__(512) void mlp_kernel(const u16* __restrict__ hbt,
    const u16* __restrict__ w1b, const int* __restrict__ paths,
    const float* __restrict__ b1, const float* __restrict__ W2,
    const float* __restrict__ b2, float* __restrict__ out)
{
  __shared__ __align__(16) u16 As[128*40];
  __shared__ __align__(16) u16 Bs[320*40];
  const int m0 = blockIdx.x*128;
  const int tid = threadIdx.x;
  const int arow = tid >> 2, ac8 = tid & 3;
  const int am = m0 + arow;
  const int ab = am / 255;
  const int w = tid >> 6, lane = tid & 63, col = lane & 15, quad = lane >> 4;
  f32x4 acc[20];
  #pragma unroll
  for (int nt=0;nt<20;nt++) acc[nt] = (f32x4){0.f,0.f,0.f,0.f};
  for (int kc=0;kc<21;kc++){
    __syncthreads();
    for (int f = tid; f < 1280; f += 512){
      int br = f >> 2, bc = f & 3;
      *(uint4*)&Bs[br*40 + bc*8] = *(const uint4*)&w1b[br*672 + kc*32 + bc*8];
    }
    int seg = (kc >= 14) ? 2 : (kc >= 7 ? 1 : 0);
    int ko = kc - seg*7;
    int it = paths[am*3 + seg];
    uint4 v = make_uint4(0u,0u,0u,0u);
    if (it >= 0){
      int t = it > 127 ? 127 : it;
      v = *(const uint4*)&hbt[(ab*128 + t)*224 + ko*32 + ac8*8];
    }
    *(uint4*)&As[arow*40 + ac8*8] = v;
    __syncthreads();
    short8 af = *(const short8*)&As[(w*16+col)*40 + quad*8];
    #pragma unroll
    for (int nt=0;nt<20;nt++){
      short8 bfrag = *(const short8*)&Bs[(nt*16+col)*40 + quad*8];
      acc[nt] = __builtin_amdgcn_mfma_f32_16x16x32_bf16(af, bfrag, acc[nt], 0, 0, 0);
    }
  }
  float pz[4][3];
  #pragma unroll
  for (int r=0;r<4;r++){ pz[r][0]=0.f; pz[r][1]=0.f; pz[r][2]=0.f; }
  #pragma unroll
  for (int nt=0;nt<20;nt++){
    int n = nt*16 + col;
    if (n < 300){
      float bb = b1[n];
      float w20 = W2[n*3+0], w21 = W2[n*3+1], w22 = W2[n*3+2];
      #pragma unroll
      for (int r=0;r<4;r++){
        float hdn = tanh_f(acc[nt][r] + bb);
        pz[r][0] = fmaf(hdn, w20, pz[r][0]);
        pz[r][1] = fmaf(hdn, w21, pz[r][1]);
        pz[r][2] = fmaf(hdn, w22, pz[r][2]);
      }
    }
  }
  #pragma unroll
  for (int off=1; off<16; off<<=1){
    #pragma unroll
    for (int r=0;r<4;r++){
      pz[r][0] += __shfl_xor(pz[r][0], off, 64);
      pz[r][1] += __shfl_xor(pz[r][1], off, 64);
      pz[r][2] += __shfl_xor(pz[r][2], off, 64);
    }
  }
  float c0 = b2[0], c1 = b2[1], c2 = b2[2];
  #pragma unroll
  for (int r=0;r<4;r++){
    float z0 = pz[r][0]+c0, z1 = pz[r][1]+c1, z2 = pz[r][2]+c2;
    float mx = fmaxf(z0, fmaxf(z1, z2));
    float e0 = __expf(z0-mx), e1 = __expf(z1-mx), e2 = __expf(z2-mx);
    float inv = 1.0f/(e0+e1+e2);
    if (col < 3){
      float pv = (col==0 ? e0 : (col==1 ? e1 : e2)) * inv;
      out[(m0 + w*16 + quad*4 + r)*3 + col] = pv;
    }
  }
}

// ---------- launch ----------
extern "C" void kernel_launch(void* const* d_in, const int* in_sizes, int n_in,
                              void* d_out, int out_size, void* d_ws, size_t ws_size,
                              hipStream_t stream)
{
  const int*   x     = (const int*)  d_in[0];
  const int*   paths = (const int*)  d_in[1];
  const float* emb   = (const float*)d_in[2];
  const float* Wih_f = (const float*)d_in[3];
  const float* Whh_f = (const float*)d_in[4];
  const float* bih_f = (const float*)d_in[5];
  const float* bhh_f = (const float*)d_in[6];
  const float* Wih_b = (const float*)d_in[7];
  const float* Whh_b = (const float*)d_in[8];
  const float* bih_b = (const float*)d_in[9];
  const float* bhh_b = (const float*)d_in[10];
  const float* W1    = (const float*)d_in[11];
  const float* b1    = (const float*)d_in[12];
  const float* W2    = (const float*)d_in[13];
  const float* b2    = (const float*)d_in[14];
  float* out = (float*)d_out;

  char* ws = (char*)d_ws;
  u16*   xe    = (u16*)  (ws + 0);          //  8,388,608 B
  u16*   wc    = (u16*)  (ws + 8388608);    //    212,992 B
  float* biasC = (float*)(ws + 8601600);    //      3,200 B
  u16*   whhH  = (u16*)  (ws + 8604800);    //    166,400 B
  u16*   w1b   = (u16*)  (ws + 8771200);    //    430,080 B
  u16*   inp   = (u16*)  (ws + 9201280);    // 52,428,800 B
  u16*   hbt   = (u16*)  (ws + 61630080);   // 14,680,064 B  (total 76,310,144)

  const int prep_total = 32768*128 + 832*128 + 800 + 83200 + 672*320 + 32768*24;
  prep_kernel<<<(prep_total + 255)/256, 256, 0, stream>>>(
      x, emb, Wih_f, Whh_f, bih_f, bhh_f, Wih_b, Whh_b, bih_b, bhh_b, W1,
      xe, wc, biasC, whhH, w1b, hbt);
  gemm1_kernel<<<dim3(512, 13), 256, 0, stream>>>(xe, wc, biasC, inp);
  lstm_kernel<<<512, 448, 0, stream>>>(inp, whhH, hbt);
  mlp_kernel<<<510, 512, 0, stream>>>(hbt, w1b, paths, b1, W2, b2, out);
}